// Round 2
// baseline (5547.103 us; speedup 1.0000x reference)
//
#include <hip/hip_runtime.h>
#include <cstddef>
#include <cstdint>

// Problem constants (fixed by reference setup_inputs)
static constexpr int Bc   = 4;
static constexpr int Lq   = 4096;
static constexpr int Dm   = 1024;
static constexpr int Hh   = 16;
static constexpr int Dmlp = 4096;
static constexpr int Mrows = Bc * Lq;   // 16384
static constexpr int Lk1   = Lq + 1;    // 4097

// ---------------------------------------------------------------------------
// zero fill
// ---------------------------------------------------------------------------
__global__ __launch_bounds__(256)
void zero_kernel(float* __restrict__ p, int n) {
    const int i = blockIdx.x * 256 + threadIdx.x;
    if (i < n) p[i] = 0.0f;
}

// ---------------------------------------------------------------------------
// SGEMM: C[M,N] = act(A[M,K] @ W[K,N] (+bias)) (+C_prior if ACCUM) (+res1+res2)
// ACT: 0 = none, 1 = tanh(x)+1, 2 = exact-erf GELU
// 128x128 tile, BK=16, 256 threads, 8x8 per thread. Strides lda/ldw/ldc.
// ---------------------------------------------------------------------------
template<int ACT, bool RES, bool ACCUM, bool BIAS>
__global__ __launch_bounds__(256, 2)
void sgemm_kernel(const float* __restrict__ A, int lda,
                  const float* __restrict__ W, int ldw,
                  const float* __restrict__ bias,
                  float* __restrict__ C, int ldc,
                  const float* __restrict__ res1, const float* __restrict__ res2,
                  int M, int N, int K) {
    __shared__ float As[16][128];   // transposed A tile: As[k][m]
    __shared__ float Bs[16][128];   // Bs[k][n]
    const int tid  = threadIdx.x;
    const int brow = blockIdx.y * 128;
    const int bcol = blockIdx.x * 128;
    const int tx = tid & 15;        // col group
    const int ty = tid >> 4;        // row group
    const int arow = tid >> 2;          // 0..63
    const int acol = (tid & 3) << 2;    // 0,4,8,12
    const int brw = tid >> 5;           // 0..7
    const int bcl = (tid & 31) << 2;    // 0..124

    float acc[8][8] = {};

    for (int k0 = 0; k0 < K; k0 += 16) {
        #pragma unroll
        for (int p = 0; p < 2; ++p) {
            float4 v = *(const float4*)&A[(size_t)(brow + arow + p * 64) * lda + k0 + acol];
            As[acol + 0][arow + p * 64] = v.x;
            As[acol + 1][arow + p * 64] = v.y;
            As[acol + 2][arow + p * 64] = v.z;
            As[acol + 3][arow + p * 64] = v.w;
        }
        #pragma unroll
        for (int p = 0; p < 2; ++p) {
            *(float4*)&Bs[brw + p * 8][bcl] =
                *(const float4*)&W[(size_t)(k0 + brw + p * 8) * ldw + bcol + bcl];
        }
        __syncthreads();
        #pragma unroll
        for (int kk = 0; kk < 16; ++kk) {
            float ra[8], rb[8];
            *(float4*)&ra[0] = *(float4*)&As[kk][ty * 8];
            *(float4*)&ra[4] = *(float4*)&As[kk][ty * 8 + 4];
            *(float4*)&rb[0] = *(float4*)&Bs[kk][tx * 8];
            *(float4*)&rb[4] = *(float4*)&Bs[kk][tx * 8 + 4];
            #pragma unroll
            for (int i = 0; i < 8; ++i)
                #pragma unroll
                for (int j = 0; j < 8; ++j)
                    acc[i][j] = fmaf(ra[i], rb[j], acc[i][j]);
        }
        __syncthreads();
    }

    #pragma unroll
    for (int i = 0; i < 8; ++i) {
        const size_t m = (size_t)brow + ty * 8 + i;
        #pragma unroll
        for (int j = 0; j < 8; j += 4) {
            const int n = bcol + tx * 8 + j;
            float bb[4] = {0.f, 0.f, 0.f, 0.f};
            if (BIAS) {
                float4 bv = *(const float4*)&bias[n];
                bb[0] = bv.x; bb[1] = bv.y; bb[2] = bv.z; bb[3] = bv.w;
            }
            float o[4];
            #pragma unroll
            for (int q = 0; q < 4; ++q) {
                float v = acc[i][j + q] + bb[q];
                if (ACT == 1) v = tanhf(v) + 1.0f;
                if (ACT == 2) v = 0.5f * v * (1.0f + erff(v * 0.70710678118654752f));
                o[q] = v;
            }
            float* cp = &C[m * ldc + n];
            if (ACCUM) {
                float4 pr = *(const float4*)cp;
                o[0] += pr.x; o[1] += pr.y; o[2] += pr.z; o[3] += pr.w;
            }
            if (RES) {
                float4 r1 = *(const float4*)&res1[m * ldc + n];
                float4 r2 = *(const float4*)&res2[m * ldc + n];
                o[0] += r1.x + r2.x; o[1] += r1.y + r2.y;
                o[2] += r1.z + r2.z; o[3] += r1.w + r2.w;
            }
            float4 ov = { o[0], o[1], o[2], o[3] };
            *(float4*)cp = ov;
        }
    }
}

// ---------------------------------------------------------------------------
// LayerNorm over last dim (1024), one block (256 thr) per row, in-place safe.
// ---------------------------------------------------------------------------
__global__ __launch_bounds__(256)
void ln1024_kernel(const float* __restrict__ in, float* __restrict__ outp,
                   const float* __restrict__ g, const float* __restrict__ be) {
    const size_t base = (size_t)blockIdx.x * Dm;
    const int tid = threadIdx.x;
    float4 v = *(const float4*)&in[base + tid * 4];
    float s  = v.x + v.y + v.z + v.w;
    float sq = v.x * v.x + v.y * v.y + v.z * v.z + v.w * v.w;
    #pragma unroll
    for (int off = 32; off > 0; off >>= 1) {
        s  += __shfl_down(s,  off, 64);
        sq += __shfl_down(sq, off, 64);
    }
    __shared__ float rs[4], rq[4];
    const int lane = tid & 63, w = tid >> 6;
    if (lane == 0) { rs[w] = s; rq[w] = sq; }
    __syncthreads();
    s  = rs[0] + rs[1] + rs[2] + rs[3];
    sq = rq[0] + rq[1] + rq[2] + rq[3];
    const float mean = s * (1.0f / 1024.0f);
    const float var  = sq * (1.0f / 1024.0f) - mean * mean;
    const float inv  = rsqrtf(var + 1e-5f);
    float4 gv = *(const float4*)&g[tid * 4];
    float4 bv = *(const float4*)&be[tid * 4];
    float4 o;
    o.x = (v.x - mean) * inv * gv.x + bv.x;
    o.y = (v.y - mean) * inv * gv.y + bv.y;
    o.z = (v.z - mean) * inv * gv.z + bv.z;
    o.w = (v.w - mean) * inv * gv.w + bv.w;
    *(float4*)&outp[base + tid * 4] = o;
}

// ---------------------------------------------------------------------------
// q_probe[b, c] = (1/(L*sqrt(D))) * sum_l Q[b, l, c]
// grid (Dm/256, 16, B); atomic accumulate into zeroed qp.
// ---------------------------------------------------------------------------
__global__ __launch_bounds__(256)
void qprobe_kernel(const float* __restrict__ Q, float* __restrict__ qp) {
    const int b = blockIdx.z;
    const int col = blockIdx.x * 256 + threadIdx.x;
    const int lchunk = Lq / 16;
    const int l0 = blockIdx.y * lchunk;
    const float* p = Q + ((size_t)b * Lq + l0) * Dm + col;
    float s = 0.f;
    for (int l = 0; l < lchunk; ++l, p += Dm) s += *p;
    atomicAdd(&qp[b * Dm + col], s * (1.0f / (4096.0f * 8.0f)));
}

// ---------------------------------------------------------------------------
// logits[bh, k] = q_probe[b,h,:] . Kh[b,h,k,:]; k=0 (zero token) -> 0
// grid (Lq/256, B*H)
// ---------------------------------------------------------------------------
__global__ __launch_bounds__(256)
void logits_kernel(const float* __restrict__ Kc, const float* __restrict__ qp,
                   float* __restrict__ score) {
    const int bh = blockIdx.y, b = bh >> 4, h = bh & 15;
    __shared__ float q[64];
    if (threadIdx.x < 64) q[threadIdx.x] = qp[b * Dm + h * 64 + threadIdx.x];
    __syncthreads();
    const int kr = blockIdx.x * 256 + threadIdx.x;   // token k = kr+1
    const float4* krp = (const float4*)&Kc[((size_t)b * Lq + kr) * Dm + h * 64];
    float s = 0.f;
    #pragma unroll
    for (int i = 0; i < 16; ++i) {
        float4 v = krp[i];
        s += q[i * 4 + 0] * v.x + q[i * 4 + 1] * v.y
           + q[i * 4 + 2] * v.z + q[i * 4 + 3] * v.w;
    }
    score[(size_t)bh * Lk1 + kr + 1] = s;
    if (blockIdx.x == 0 && threadIdx.x == 0) score[(size_t)bh * Lk1] = 0.f;
}

// ---------------------------------------------------------------------------
// softmax over Lk1=4097 entries, one block per (b,h), in-place on score.
// ---------------------------------------------------------------------------
__global__ __launch_bounds__(256)
void softmax4097_kernel(float* __restrict__ sc) {
    __shared__ float buf[Lk1];
    __shared__ float red[8];
    const size_t base = (size_t)blockIdx.x * Lk1;
    const int tid = threadIdx.x;
    float mx = -1e30f;
    for (int i = tid; i < Lk1; i += 256) { float v = sc[base + i]; buf[i] = v; mx = fmaxf(mx, v); }
    #pragma unroll
    for (int off = 32; off > 0; off >>= 1) mx = fmaxf(mx, __shfl_down(mx, off, 64));
    const int lane = tid & 63, w = tid >> 6;
    if (lane == 0) red[w] = mx;
    __syncthreads();
    mx = fmaxf(fmaxf(red[0], red[1]), fmaxf(red[2], red[3]));
    float sum = 0.f;
    for (int i = tid; i < Lk1; i += 256) { float e = expf(buf[i] - mx); buf[i] = e; sum += e; }
    #pragma unroll
    for (int off = 32; off > 0; off >>= 1) sum += __shfl_down(sum, off, 64);
    if (lane == 0) red[4 + w] = sum;
    __syncthreads();
    sum = red[4] + red[5] + red[6] + red[7];
    const float inv = 1.0f / sum;
    for (int i = tid; i < Lk1; i += 256) sc[base + i] = buf[i] * inv;
}

// ---------------------------------------------------------------------------
// KV[b,h,d,e] += sum_l (score[l+1]*phiK[l,d]) * V[l,e]  (zero token: V=0)
// grid (8, B*H), 256 threads, 4x4 per thread, atomic reduce across l-chunks.
// ---------------------------------------------------------------------------
__global__ __launch_bounds__(256)
void kv_kernel(const float* __restrict__ phiK, const float* __restrict__ Vc,
               const float* __restrict__ sc, float* __restrict__ KV) {
    const int bh = blockIdx.y, b = bh >> 4, h = bh & 15;
    const int lchunk = Lq / 8;
    const int l0 = blockIdx.x * lchunk;
    __shared__ float pk[8][64];
    __shared__ float vv[8][64];
    const int i0 = (threadIdx.x >> 4) << 2;
    const int j0 = (threadIdx.x & 15) << 2;
    float acc[4][4] = {};
    for (int lb = l0; lb < l0 + lchunk; lb += 8) {
        #pragma unroll
        for (int q = 0; q < 2; ++q) {
            const int idx = threadIdx.x + q * 256;
            const int r = idx >> 6, c = idx & 63;
            const float scv = sc[(size_t)bh * Lk1 + lb + r + 1];
            const size_t off = ((size_t)b * Lq + lb + r) * Dm + h * 64 + c;
            pk[r][c] = phiK[off] * scv;
            vv[r][c] = Vc[off];
        }
        __syncthreads();
        #pragma unroll
        for (int r = 0; r < 8; ++r) {
            float ra[4], rb[4];
            #pragma unroll
            for (int i = 0; i < 4; ++i) ra[i] = pk[r][i0 + i];
            #pragma unroll
            for (int j = 0; j < 4; ++j) rb[j] = vv[r][j0 + j];
            #pragma unroll
            for (int i = 0; i < 4; ++i)
                #pragma unroll
                for (int j = 0; j < 4; ++j)
                    acc[i][j] = fmaf(ra[i], rb[j], acc[i][j]);
        }
        __syncthreads();
    }
    #pragma unroll
    for (int i = 0; i < 4; ++i)
        #pragma unroll
        for (int j = 0; j < 4; ++j)
            atomicAdd(&KV[((size_t)bh * 64 + i0 + i) * 64 + j0 + j], acc[i][j]);
}

// ---------------------------------------------------------------------------
// Ksum[b,h,d] = sum_k score[k]*phiK[k,d], incl. zero token phi = tanh(bfk)+1
// grid (8, B*H), 64 threads.
// ---------------------------------------------------------------------------
__global__ __launch_bounds__(64)
void ksum_kernel(const float* __restrict__ phiK, const float* __restrict__ sc,
                 const float* __restrict__ bfk, float* __restrict__ Ksum) {
    const int bh = blockIdx.y, b = bh >> 4, h = bh & 15;
    const int lchunk = Lq / 8;
    const int l0 = blockIdx.x * lchunk;
    const int dd = threadIdx.x;
    float s = 0.f;
    const float* pp = &phiK[((size_t)b * Lq + l0) * Dm + h * 64 + dd];
    const float* sp = &sc[(size_t)bh * Lk1 + l0 + 1];
    for (int l = 0; l < lchunk; ++l, pp += Dm) s = fmaf(*pp, sp[l], s);
    if (blockIdx.x == 0) s += sc[(size_t)bh * Lk1] * (tanhf(bfk[h * 64 + dd]) + 1.0f);
    atomicAdd(&Ksum[bh * 64 + dd], s);
}

// ---------------------------------------------------------------------------
// out[b,l,h*64+e] = (phiQ[b,l,h,:] @ KV[b,h,:,e]) / (phiQ . Ksum + 1e-6)
// one block (256 thr) per row; 4 output cols per thread.
// ---------------------------------------------------------------------------
__global__ __launch_bounds__(256)
void attnout_kernel(const float* __restrict__ phiQ, const float* __restrict__ KV,
                    const float* __restrict__ Ksum, float* __restrict__ outp) {
    const size_t row = blockIdx.x;
    const int b = (int)(row / Lq);
    __shared__ float pq[1024];
    __shared__ float den[16];
    const int tid = threadIdx.x;
    *(float4*)&pq[tid * 4] = *(const float4*)&phiQ[row * Dm + tid * 4];
    __syncthreads();
    if (tid < 16) {
        float s = 0.f;
        const float* ks = &Ksum[(b * 16 + tid) * 64];
        for (int dd = 0; dd < 64; ++dd) s = fmaf(pq[tid * 64 + dd], ks[dd], s);
        den[tid] = 1.0f / (s + 1e-6f);
    }
    __syncthreads();
    const int c = tid * 4;
    const int h = c >> 6;
    const float* kvb = &KV[(size_t)(b * 16 + h) * 4096 + (c & 63)];
    float4 acc = { 0.f, 0.f, 0.f, 0.f };
    for (int dd = 0; dd < 64; ++dd) {
        const float qv = pq[h * 64 + dd];
        float4 kv = *(const float4*)&kvb[(size_t)dd * 64];
        acc.x = fmaf(qv, kv.x, acc.x);
        acc.y = fmaf(qv, kv.y, acc.y);
        acc.z = fmaf(qv, kv.z, acc.z);
        acc.w = fmaf(qv, kv.w, acc.w);
    }
    const float dn = den[h];
    acc.x *= dn; acc.y *= dn; acc.z *= dn; acc.w *= dn;
    *(float4*)&outp[row * Dm + c] = acc;
}

// ---------------------------------------------------------------------------
extern "C" void kernel_launch(void* const* d_in, const int* in_sizes, int n_in,
                              void* d_out, int out_size, void* d_ws, size_t ws_size,
                              hipStream_t stream) {
    const float* x     = (const float*)d_in[0];
    const float* Wq    = (const float*)d_in[1];
    const float* bq    = (const float*)d_in[2];
    const float* gq    = (const float*)d_in[3];
    const float* betaq = (const float*)d_in[4];
    const float* Wk    = (const float*)d_in[5];
    const float* bk    = (const float*)d_in[6];
    const float* gk    = (const float*)d_in[7];
    const float* betak = (const float*)d_in[8];
    const float* Wv    = (const float*)d_in[9];
    const float* bv    = (const float*)d_in[10];
    const float* gv    = (const float*)d_in[11];
    const float* betav = (const float*)d_in[12];
    const float* Wfq   = (const float*)d_in[13];
    const float* bfq   = (const float*)d_in[14];
    const float* Wfk   = (const float*)d_in[15];
    const float* bfk   = (const float*)d_in[16];
    const float* ga    = (const float*)d_in[17];
    const float* ba    = (const float*)d_in[18];
    const float* W1    = (const float*)d_in[19];
    const float* b1    = (const float*)d_in[20];
    const float* W2    = (const float*)d_in[21];
    const float* b2    = (const float*)d_in[22];
    float* outp = (float*)d_out;

    // Workspace layout: 2 big slots (64 MB each) + small region.
    // Peak usage ~130.2 MB. d_out doubles as the phiK buffer (dead before
    // the MLP output GEMM starts writing the real output).
    float* ws = (float*)d_ws;
    const size_t Md = (size_t)Mrows * Dm;      // 16,777,216 floats
    float* S0 = ws;            // Q_ln -> V_ln -> attn_out/a
    float* S1 = ws + Md;       // K_ln -> phiQ -> h1 chunk
    float* qp    = ws + 2 * Md;                 // 4096
    float* KV    = qp + 4096;                   // 262,144
    float* Ksum  = KV + (size_t)64 * 64 * 64;   // 4096
    float* score = Ksum + 4096;                 // 64*4097 = 262,208
    float* phiK  = outp;                        // borrow d_out for phiK

    const dim3 blk(256);
    const dim3 gemm_d(Dm / 128, Mrows / 128);   // (8,128)

    // zero qp + KV + Ksum (contiguous: 4096 + 262144 + 4096 floats)
    {
        const int nz = 4096 + 64 * 64 * 64 + 4096;
        zero_kernel<<<(nz + 255) / 256, blk, 0, stream>>>(qp, nz);
    }

    // 1) Q/K projections + LayerNorm
    sgemm_kernel<0, false, false, true><<<gemm_d, blk, 0, stream>>>(
        x, Dm, Wq, Dm, bq, S0, Dm, nullptr, nullptr, Mrows, Dm, Dm);
    ln1024_kernel<<<Mrows, blk, 0, stream>>>(S0, S0, gq, betaq);
    sgemm_kernel<0, false, false, true><<<gemm_d, blk, 0, stream>>>(
        x, Dm, Wk, Dm, bk, S1, Dm, nullptr, nullptr, Mrows, Dm, Dm);
    ln1024_kernel<<<Mrows, blk, 0, stream>>>(S1, S1, gk, betak);

    // 2) probe + softmax gating (uses Q_ln in S0, K_ln in S1)
    qprobe_kernel<<<dim3(Dm / 256, 16, Bc), blk, 0, stream>>>(S0, qp);
    logits_kernel<<<dim3(Lq / 256, Bc * Hh), blk, 0, stream>>>(S1, qp, score);
    softmax4097_kernel<<<Bc * Hh, blk, 0, stream>>>(score);

    // 3) feature maps: phiK (S1 -> OUT), then phiQ (S0 -> S1)
    sgemm_kernel<1, false, false, true><<<gemm_d, blk, 0, stream>>>(
        S1, Dm, Wfk, Dm, bfk, phiK, Dm, nullptr, nullptr, Mrows, Dm, Dm);
    sgemm_kernel<1, false, false, true><<<gemm_d, blk, 0, stream>>>(
        S0, Dm, Wfq, Dm, bfq, S1, Dm, nullptr, nullptr, Mrows, Dm, Dm);

    // 4) V projection + LN into S0 (Q_ln dead)
    sgemm_kernel<0, false, false, true><<<gemm_d, blk, 0, stream>>>(
        x, Dm, Wv, Dm, bv, S0, Dm, nullptr, nullptr, Mrows, Dm, Dm);
    ln1024_kernel<<<Mrows, blk, 0, stream>>>(S0, S0, gv, betav);

    // 5) KV and Ksum reductions (zero token handled analytically)
    kv_kernel<<<dim3(8, Bc * Hh), blk, 0, stream>>>(phiK, S0, score, KV);
    ksum_kernel<<<dim3(8, Bc * Hh), dim3(64), 0, stream>>>(phiK, score, bfk, Ksum);

    // 6) attention output -> S0 (V dead), then attn LayerNorm -> a in S0
    attnout_kernel<<<Mrows, blk, 0, stream>>>(S1, KV, Ksum, S0);
    ln1024_kernel<<<Mrows, blk, 0, stream>>>(S0, S0, ga, ba);

    // 7) MLP in 4 chunks of Dmlp/4 = 1024: h1_c = gelu(a@W1_c+b1_c) -> S1,
    //    out (+)= h1_c @ W2_c; chunk 0 adds b2, chunk 3 adds residuals a + x.
    for (int c = 0; c < 4; ++c) {
        sgemm_kernel<2, false, false, true><<<gemm_d, blk, 0, stream>>>(
            S0, Dm, W1 + c * 1024, Dmlp, b1 + c * 1024, S1, 1024,
            nullptr, nullptr, Mrows, 1024, Dm);
        if (c == 0) {
            sgemm_kernel<0, false, false, true><<<gemm_d, blk, 0, stream>>>(
                S1, 1024, W2 + (size_t)c * 1024 * Dm, Dm, b2, outp, Dm,
                nullptr, nullptr, Mrows, Dm, 1024);
        } else if (c < 3) {
            sgemm_kernel<0, false, true, false><<<gemm_d, blk, 0, stream>>>(
                S1, 1024, W2 + (size_t)c * 1024 * Dm, Dm, nullptr, outp, Dm,
                nullptr, nullptr, Mrows, Dm, 1024);
        } else {
            sgemm_kernel<0, true, true, false><<<gemm_d, blk, 0, stream>>>(
                S1, 1024, W2 + (size_t)c * 1024 * Dm, Dm, nullptr, outp, Dm,
                S0, x, Mrows, Dm, 1024);
        }
    }
}

// Round 3
// 1099.135 us; speedup vs baseline: 5.0468x; 5.0468x over previous
//
#include <hip/hip_runtime.h>
#include <cstddef>
#include <cstdint>

static constexpr int Bc   = 4;
static constexpr int Lq   = 4096;
static constexpr int Dm   = 1024;
static constexpr int Dmlp = 4096;
static constexpr int Mrows = Bc * Lq;   // 16384
static constexpr int Lk1   = Lq + 1;    // 4097

typedef unsigned short u16;
typedef __bf16 bf16_t;
typedef bf16_t bf16x8 __attribute__((ext_vector_type(8)));
typedef float  f32x4  __attribute__((ext_vector_type(4)));

__device__ __forceinline__ u16 f2b(float f) {
    uint32_t u = __builtin_bit_cast(uint32_t, f);
    return (u16)((u + 0x7FFFu + ((u >> 16) & 1u)) >> 16);
}
__device__ __forceinline__ float b2f(u16 h) {
    uint32_t u = ((uint32_t)h) << 16;
    return __builtin_bit_cast(float, u);
}

#define GLL16(gsrc, ldst) \
    __builtin_amdgcn_global_load_lds( \
        (const __attribute__((address_space(1))) void*)(gsrc), \
        (__attribute__((address_space(3))) void*)(ldst), 16, 0, 0)

// ---------------------------------------------------------------------------
// zero fill
// ---------------------------------------------------------------------------
__global__ __launch_bounds__(256)
void zero_kernel(float* __restrict__ p, int n) {
    const int i = blockIdx.x * 256 + threadIdx.x;
    if (i < n) p[i] = 0.0f;
}

// ---------------------------------------------------------------------------
// fp32 -> bf16 elementwise convert (x -> xb), vectorized
// ---------------------------------------------------------------------------
__global__ __launch_bounds__(256)
void cvt_bf16_kernel(const float* __restrict__ in, u16* __restrict__ outp, int n) {
    for (int i = (blockIdx.x * 256 + threadIdx.x) * 4; i < n; i += gridDim.x * 256 * 4) {
        float4 v = *(const float4*)&in[i];
        ushort4 o = { f2b(v.x), f2b(v.y), f2b(v.z), f2b(v.w) };
        *(ushort4*)&outp[i] = o;
    }
}

// ---------------------------------------------------------------------------
// W [R][C] fp32  ->  Wt [C][R] bf16, 64x64 LDS tile
// ---------------------------------------------------------------------------
__global__ __launch_bounds__(256)
void transpose_bf16_kernel(const float* __restrict__ in, u16* __restrict__ outp,
                           int R, int C) {
    __shared__ float tile[64][65];
    const int r0 = blockIdx.y * 64, c0 = blockIdx.x * 64;
    const int t = threadIdx.x;
    const int lr = t >> 2, lc0 = (t & 3) * 16;
    #pragma unroll
    for (int j = 0; j < 4; ++j) {
        float4 v = *(const float4*)&in[(size_t)(r0 + lr) * C + c0 + lc0 + j * 4];
        tile[lr][lc0 + j * 4 + 0] = v.x;
        tile[lr][lc0 + j * 4 + 1] = v.y;
        tile[lr][lc0 + j * 4 + 2] = v.z;
        tile[lr][lc0 + j * 4 + 3] = v.w;
    }
    __syncthreads();
    const int oc = t >> 2, rr0 = (t & 3) * 16;
    union { u16 u[16]; uint4 v[2]; } pk;
    #pragma unroll
    for (int j = 0; j < 16; ++j) pk.u[j] = f2b(tile[rr0 + j][oc]);
    u16* po = &outp[(size_t)(c0 + oc) * R + r0 + rr0];
    *(uint4*)&po[0] = pk.v[0];
    *(uint4*)&po[8] = pk.v[1];
}

// ---------------------------------------------------------------------------
// MFMA bf16 GEMM: C[M,N] = act(A[M,K] @ Wt[N,K]^T (+bias)) (+C)(+res1+res2)
// 128x128 tile, BK=32, 4 waves (2x2), 16x16x32 MFMA, global_load_lds staging.
// ACT: 0 none, 1 tanh+1, 2 exact GELU. OBF16: write bf16, else fp32.
// ---------------------------------------------------------------------------
template<int ACT, bool RES, bool ACCUM, bool BIAS, bool OBF16>
__global__ __launch_bounds__(256, 2)
void mfma_gemm(const u16* __restrict__ A, int ldA,
               const u16* __restrict__ Bt, int ldB,
               const float* __restrict__ bias,
               void* __restrict__ Cout,
               const u16* __restrict__ res1, const float* __restrict__ res2,
               int M, int N, int K) {
    __shared__ u16 As[4096];   // [128][32]
    __shared__ u16 Bs[4096];   // [128][32]
    const int tid  = threadIdx.x;
    const int brow = blockIdx.y * 128;
    const int bcol = blockIdx.x * 128;
    const int l   = tid & 63;
    const int w   = tid >> 6;
    const int wr  = (w >> 1) * 64;
    const int wc  = (w & 1) * 64;
    const int l16 = l & 15, l4 = l >> 4;

    const u16* ga = A  + (size_t)(brow + (tid >> 2)) * ldA + (tid & 3) * 8;
    const u16* gb = Bt + (size_t)(bcol + (tid >> 2)) * ldB + (tid & 3) * 8;
    const size_t gsA = (size_t)64 * ldA;
    const size_t gsB = (size_t)64 * ldB;
    u16* lA = As + tid * 8;
    u16* lB = Bs + tid * 8;

    f32x4 acc[4][4];
    const f32x4 zf = {0.f, 0.f, 0.f, 0.f};
    #pragma unroll
    for (int m = 0; m < 4; ++m)
        #pragma unroll
        for (int n = 0; n < 4; ++n) acc[m][n] = zf;

    const int aoff = (wr + l16) * 32 + l4 * 8;   // + m*512
    const int boff = (wc + l16) * 32 + l4 * 8;   // + n*512

    for (int k0 = 0; k0 < K; k0 += 32) {
        GLL16(ga,       lA);
        GLL16(ga + gsA, lA + 2048);
        GLL16(gb,       lB);
        GLL16(gb + gsB, lB + 2048);
        ga += 32; gb += 32;
        __syncthreads();               // drains vmcnt(0) + barrier
        bf16x8 af[4], bfv[4];
        #pragma unroll
        for (int m = 0; m < 4; ++m) af[m]  = *(const bf16x8*)&As[aoff + m * 512];
        #pragma unroll
        for (int n = 0; n < 4; ++n) bfv[n] = *(const bf16x8*)&Bs[boff + n * 512];
        #pragma unroll
        for (int m = 0; m < 4; ++m)
            #pragma unroll
            for (int n = 0; n < 4; ++n)
                acc[m][n] = __builtin_amdgcn_mfma_f32_16x16x32_bf16(
                    af[m], bfv[n], acc[m][n], 0, 0, 0);
        __syncthreads();
    }

    float bvn[4];
    #pragma unroll
    for (int n = 0; n < 4; ++n)
        bvn[n] = BIAS ? bias[bcol + wc + n * 16 + l16] : 0.f;

    #pragma unroll
    for (int m = 0; m < 4; ++m) {
        #pragma unroll
        for (int q = 0; q < 4; ++q) {
            const size_t row = (size_t)brow + wr + m * 16 + l4 * 4 + q;
            #pragma unroll
            for (int n = 0; n < 4; ++n) {
                const size_t col = (size_t)bcol + wc + n * 16 + l16;
                float v = acc[m][n][q] + bvn[n];
                if (ACT == 1) v = tanhf(v) + 1.0f;
                if (ACT == 2) v = 0.5f * v * (1.0f + erff(v * 0.70710678118654752f));
                const size_t idx = row * (size_t)N + col;
                if (OBF16) {
                    ((u16*)Cout)[idx] = f2b(v);
                } else {
                    float* Cf = (float*)Cout;
                    if (ACCUM) v += Cf[idx];
                    if (RES)   v += b2f(res1[idx]) + res2[idx];
                    Cf[idx] = v;
                }
            }
        }
    }
}

// ---------------------------------------------------------------------------
// LayerNorm(1024) on bf16, in-place safe
// ---------------------------------------------------------------------------
__global__ __launch_bounds__(256)
void ln1024_bf16_kernel(const u16* __restrict__ in, u16* __restrict__ outp,
                        const float* __restrict__ g, const float* __restrict__ be) {
    const size_t base = (size_t)blockIdx.x * Dm;
    const int tid = threadIdx.x;
    ushort4 raw = *(const ushort4*)&in[base + tid * 4];
    float v0 = b2f(raw.x), v1 = b2f(raw.y), v2 = b2f(raw.z), v3 = b2f(raw.w);
    float s  = v0 + v1 + v2 + v3;
    float sq = v0 * v0 + v1 * v1 + v2 * v2 + v3 * v3;
    #pragma unroll
    for (int off = 32; off > 0; off >>= 1) {
        s  += __shfl_down(s,  off, 64);
        sq += __shfl_down(sq, off, 64);
    }
    __shared__ float rs[4], rq[4];
    const int lane = tid & 63, wv = tid >> 6;
    if (lane == 0) { rs[wv] = s; rq[wv] = sq; }
    __syncthreads();
    s  = rs[0] + rs[1] + rs[2] + rs[3];
    sq = rq[0] + rq[1] + rq[2] + rq[3];
    const float mean = s * (1.0f / 1024.0f);
    const float var  = sq * (1.0f / 1024.0f) - mean * mean;
    const float inv  = rsqrtf(var + 1e-5f);
    float4 gv = *(const float4*)&g[tid * 4];
    float4 bv = *(const float4*)&be[tid * 4];
    ushort4 o;
    o.x = f2b((v0 - mean) * inv * gv.x + bv.x);
    o.y = f2b((v1 - mean) * inv * gv.y + bv.y);
    o.z = f2b((v2 - mean) * inv * gv.z + bv.z);
    o.w = f2b((v3 - mean) * inv * gv.w + bv.w);
    *(ushort4*)&outp[base + tid * 4] = o;
}

// ---------------------------------------------------------------------------
// q_probe[b,c] = (1/(L*sqrt(64))) * sum_l Q[b,l,c]   (Q bf16)
// ---------------------------------------------------------------------------
__global__ __launch_bounds__(256)
void qprobe_kernel(const u16* __restrict__ Q, float* __restrict__ qp) {
    const int b = blockIdx.z;
    const int col = blockIdx.x * 256 + threadIdx.x;
    const int lchunk = Lq / 16;
    const int l0 = blockIdx.y * lchunk;
    const u16* p = Q + ((size_t)b * Lq + l0) * Dm + col;
    float s = 0.f;
    for (int l = 0; l < lchunk; ++l, p += Dm) s += b2f(*p);
    atomicAdd(&qp[b * Dm + col], s * (1.0f / (4096.0f * 8.0f)));
}

// ---------------------------------------------------------------------------
// logits[bh,k] = q_probe . K row (bf16); token 0 logit = 0
// ---------------------------------------------------------------------------
__global__ __launch_bounds__(256)
void logits_kernel(const u16* __restrict__ Kc, const float* __restrict__ qp,
                   float* __restrict__ score) {
    const int bh = blockIdx.y, b = bh >> 4, h = bh & 15;
    __shared__ float q[64];
    if (threadIdx.x < 64) q[threadIdx.x] = qp[b * Dm + h * 64 + threadIdx.x];
    __syncthreads();
    const int kr = blockIdx.x * 256 + threadIdx.x;
    const ushort4* krp = (const ushort4*)&Kc[((size_t)b * Lq + kr) * Dm + h * 64];
    float s = 0.f;
    #pragma unroll
    for (int i = 0; i < 16; ++i) {
        ushort4 v = krp[i];
        s += q[i * 4 + 0] * b2f(v.x) + q[i * 4 + 1] * b2f(v.y)
           + q[i * 4 + 2] * b2f(v.z) + q[i * 4 + 3] * b2f(v.w);
    }
    score[(size_t)bh * Lk1 + kr + 1] = s;
    if (blockIdx.x == 0 && threadIdx.x == 0) score[(size_t)bh * Lk1] = 0.f;
}

// ---------------------------------------------------------------------------
// softmax over 4097, one block per (b,h)
// ---------------------------------------------------------------------------
__global__ __launch_bounds__(256)
void softmax4097_kernel(float* __restrict__ sc) {
    __shared__ float buf[Lk1];
    __shared__ float red[8];
    const size_t base = (size_t)blockIdx.x * Lk1;
    const int tid = threadIdx.x;
    float mx = -1e30f;
    for (int i = tid; i < Lk1; i += 256) { float v = sc[base + i]; buf[i] = v; mx = fmaxf(mx, v); }
    #pragma unroll
    for (int off = 32; off > 0; off >>= 1) mx = fmaxf(mx, __shfl_down(mx, off, 64));
    const int lane = tid & 63, wv = tid >> 6;
    if (lane == 0) red[wv] = mx;
    __syncthreads();
    mx = fmaxf(fmaxf(red[0], red[1]), fmaxf(red[2], red[3]));
    float sum = 0.f;
    for (int i = tid; i < Lk1; i += 256) { float e = expf(buf[i] - mx); buf[i] = e; sum += e; }
    #pragma unroll
    for (int off = 32; off > 0; off >>= 1) sum += __shfl_down(sum, off, 64);
    if (lane == 0) red[4 + wv] = sum;
    __syncthreads();
    sum = red[4] + red[5] + red[6] + red[7];
    const float inv = 1.0f / sum;
    for (int i = tid; i < Lk1; i += 256) sc[base + i] = buf[i] * inv;
}

// ---------------------------------------------------------------------------
// KV[b,h,d,e] += sum_l (score[l+1]*phiK[l,d]) * V[l,e]   (bf16 inputs)
// ---------------------------------------------------------------------------
__global__ __launch_bounds__(256)
void kv_kernel(const u16* __restrict__ phiK, const u16* __restrict__ Vc,
               const float* __restrict__ sc, float* __restrict__ KV) {
    const int bh = blockIdx.y, b = bh >> 4, h = bh & 15;
    const int lchunk = Lq / 8;
    const int l0 = blockIdx.x * lchunk;
    __shared__ float pk[8][64];
    __shared__ float vv[8][64];
    const int i0 = (threadIdx.x >> 4) << 2;
    const int j0 = (threadIdx.x & 15) << 2;
    float acc[4][4] = {};
    for (int lb = l0; lb < l0 + lchunk; lb += 8) {
        #pragma unroll
        for (int q = 0; q < 2; ++q) {
            const int idx = threadIdx.x + q * 256;
            const int r = idx >> 6, c = idx & 63;
            const float scv = sc[(size_t)bh * Lk1 + lb + r + 1];
            const size_t off = ((size_t)b * Lq + lb + r) * Dm + h * 64 + c;
            pk[r][c] = b2f(phiK[off]) * scv;
            vv[r][c] = b2f(Vc[off]);
        }
        __syncthreads();
        #pragma unroll
        for (int r = 0; r < 8; ++r) {
            float ra[4], rb[4];
            #pragma unroll
            for (int i = 0; i < 4; ++i) ra[i] = pk[r][i0 + i];
            #pragma unroll
            for (int j = 0; j < 4; ++j) rb[j] = vv[r][j0 + j];
            #pragma unroll
            for (int i = 0; i < 4; ++i)
                #pragma unroll
                for (int j = 0; j < 4; ++j)
                    acc[i][j] = fmaf(ra[i], rb[j], acc[i][j]);
        }
        __syncthreads();
    }
    #pragma unroll
    for (int i = 0; i < 4; ++i)
        #pragma unroll
        for (int j = 0; j < 4; ++j)
            atomicAdd(&KV[((size_t)bh * 64 + i0 + i) * 64 + j0 + j], acc[i][j]);
}

// ---------------------------------------------------------------------------
// Ksum[b,h,d] = sum_k score[k]*phiK[k,d] incl. zero token tanh(bfk)+1
// ---------------------------------------------------------------------------
__global__ __launch_bounds__(64)
void ksum_kernel(const u16* __restrict__ phiK, const float* __restrict__ sc,
                 const float* __restrict__ bfk, float* __restrict__ Ksum) {
    const int bh = blockIdx.y, b = bh >> 4, h = bh & 15;
    const int lchunk = Lq / 8;
    const int l0 = blockIdx.x * lchunk;
    const int dd = threadIdx.x;
    float s = 0.f;
    const u16* pp = &phiK[((size_t)b * Lq + l0) * Dm + h * 64 + dd];
    const float* sp = &sc[(size_t)bh * Lk1 + l0 + 1];
    for (int l = 0; l < lchunk; ++l, pp += Dm) s = fmaf(b2f(*pp), sp[l], s);
    if (blockIdx.x == 0) s += sc[(size_t)bh * Lk1] * (tanhf(bfk[h * 64 + dd]) + 1.0f);
    atomicAdd(&Ksum[bh * 64 + dd], s);
}

// ---------------------------------------------------------------------------
// out = (phiQ @ KV) / (phiQ . Ksum + 1e-6), bf16 in, bf16 out
// ---------------------------------------------------------------------------
__global__ __launch_bounds__(256)
void attnout_kernel(const u16* __restrict__ phiQ, const float* __restrict__ KV,
                    const float* __restrict__ Ksum, u16* __restrict__ outp) {
    const size_t row = blockIdx.x;
    const int b = (int)(row / Lq);
    __shared__ float pq[1024];
    __shared__ float den[16];
    const int tid = threadIdx.x;
    {
        ushort4 raw = *(const ushort4*)&phiQ[row * Dm + tid * 4];
        pq[tid * 4 + 0] = b2f(raw.x);
        pq[tid * 4 + 1] = b2f(raw.y);
        pq[tid * 4 + 2] = b2f(raw.z);
        pq[tid * 4 + 3] = b2f(raw.w);
    }
    __syncthreads();
    if (tid < 16) {
        float s = 0.f;
        const float* ks = &Ksum[(b * 16 + tid) * 64];
        for (int dd = 0; dd < 64; ++dd) s = fmaf(pq[tid * 64 + dd], ks[dd], s);
        den[tid] = 1.0f / (s + 1e-6f);
    }
    __syncthreads();
    const int c = tid * 4;
    const int h = c >> 6;
    const float* kvb = &KV[(size_t)(b * 16 + h) * 4096 + (c & 63)];
    float4 acc = { 0.f, 0.f, 0.f, 0.f };
    for (int dd = 0; dd < 64; ++dd) {
        const float qv = pq[h * 64 + dd];
        float4 kv = *(const float4*)&kvb[(size_t)dd * 64];
        acc.x = fmaf(qv, kv.x, acc.x);
        acc.y = fmaf(qv, kv.y, acc.y);
        acc.z = fmaf(qv, kv.z, acc.z);
        acc.w = fmaf(qv, kv.w, acc.w);
    }
    const float dn = den[h];
    ushort4 o = { f2b(acc.x * dn), f2b(acc.y * dn), f2b(acc.z * dn), f2b(acc.w * dn) };
    *(ushort4*)&outp[row * Dm + c] = o;
}

// ---------------------------------------------------------------------------
extern "C" void kernel_launch(void* const* d_in, const int* in_sizes, int n_in,
                              void* d_out, int out_size, void* d_ws, size_t ws_size,
                              hipStream_t stream) {
    const float* x     = (const float*)d_in[0];
    const float* Wq    = (const float*)d_in[1];
    const float* bq    = (const float*)d_in[2];
    const float* gq    = (const float*)d_in[3];
    const float* betaq = (const float*)d_in[4];
    const float* Wk    = (const float*)d_in[5];
    const float* bk    = (const float*)d_in[6];
    const float* gk    = (const float*)d_in[7];
    const float* betak = (const float*)d_in[8];
    const float* Wv    = (const float*)d_in[9];
    const float* bv    = (const float*)d_in[10];
    const float* gv    = (const float*)d_in[11];
    const float* betav = (const float*)d_in[12];
    const float* Wfq   = (const float*)d_in[13];
    const float* bfq   = (const float*)d_in[14];
    const float* Wfk   = (const float*)d_in[15];
    const float* bfk   = (const float*)d_in[16];
    const float* ga    = (const float*)d_in[17];
    const float* ba    = (const float*)d_in[18];
    const float* W1    = (const float*)d_in[19];
    const float* b1    = (const float*)d_in[20];
    const float* W2    = (const float*)d_in[21];
    const float* b2    = (const float*)d_in[22];
    float* outp = (float*)d_out;

    // ---- workspace layout (~124 MB) ----
    uint8_t* wsb = (uint8_t*)d_ws;
    size_t off = 0;
    auto alloc = [&](size_t bytes) { void* p = wsb + off; off += bytes; return p; };
    const size_t Md = (size_t)Mrows * Dm;   // 16,777,216
    u16* B0   = (u16*)alloc(Md * 2);        // xb -> h1 chunk
    u16* B1   = (u16*)alloc(Md * 2);        // Q_ln -> V_ln
    u16* B2   = (u16*)alloc(Md * 2);        // K_ln -> attn_out/a
    u16* Wtq  = (u16*)alloc((size_t)Dm * Dm * 2);
    u16* Wtk  = (u16*)alloc((size_t)Dm * Dm * 2);
    u16* Wtv  = (u16*)alloc((size_t)Dm * Dm * 2);
    u16* Wtfq = (u16*)alloc((size_t)Dm * Dm * 2);
    u16* Wtfk = (u16*)alloc((size_t)Dm * Dm * 2);
    u16* Wt1  = (u16*)alloc((size_t)Dm * Dmlp * 2);   // [4096][1024]
    u16* Wt2  = (u16*)alloc((size_t)Dm * Dmlp * 2);   // [1024][4096]
    float* qp    = (float*)alloc(4096 * 4);
    float* KV    = (float*)alloc((size_t)64 * 64 * 64 * 4);
    float* Ksum  = (float*)alloc(4096 * 4);
    float* score = (float*)alloc((size_t)64 * Lk1 * 4);
    u16* PK = (u16*)outp;        // borrow d_out (bf16): first half
    u16* PQ = (u16*)outp + Md;   // second half

    const dim3 blk(256);
    const dim3 g_gemm(8, 128);       // N=1024, M=16384

    // 0) converts + transposes
    cvt_bf16_kernel<<<2048, blk, 0, stream>>>(x, B0, (int)Md);
    transpose_bf16_kernel<<<dim3(16, 16), blk, 0, stream>>>(Wq,  Wtq,  Dm, Dm);
    transpose_bf16_kernel<<<dim3(16, 16), blk, 0, stream>>>(Wk,  Wtk,  Dm, Dm);
    transpose_bf16_kernel<<<dim3(16, 16), blk, 0, stream>>>(Wv,  Wtv,  Dm, Dm);
    transpose_bf16_kernel<<<dim3(16, 16), blk, 0, stream>>>(Wfq, Wtfq, Dm, Dm);
    transpose_bf16_kernel<<<dim3(16, 16), blk, 0, stream>>>(Wfk, Wtfk, Dm, Dm);
    transpose_bf16_kernel<<<dim3(64, 16), blk, 0, stream>>>(W1,  Wt1,  Dm, Dmlp);
    transpose_bf16_kernel<<<dim3(16, 64), blk, 0, stream>>>(W2,  Wt2,  Dmlp, Dm);
    {   // zero qp + KV + Ksum (contiguous)
        const int nz = 4096 + 64 * 64 * 64 + 4096;
        zero_kernel<<<(nz + 255) / 256, blk, 0, stream>>>(qp, nz);
    }

    // 1) Q = LN(x@Wq+bq) -> B1 ; K = LN(x@Wk+bk) -> B2
    mfma_gemm<0, false, false, true, true><<<g_gemm, blk, 0, stream>>>(
        B0, Dm, Wtq, Dm, bq, B1, nullptr, nullptr, Mrows, Dm, Dm);
    ln1024_bf16_kernel<<<Mrows, blk, 0, stream>>>(B1, B1, gq, betaq);
    mfma_gemm<0, false, false, true, true><<<g_gemm, blk, 0, stream>>>(
        B0, Dm, Wtk, Dm, bk, B2, nullptr, nullptr, Mrows, Dm, Dm);
    ln1024_bf16_kernel<<<Mrows, blk, 0, stream>>>(B2, B2, gk, betak);

    // 2) probe softmax gating
    qprobe_kernel<<<dim3(Dm / 256, 16, Bc), blk, 0, stream>>>(B1, qp);
    logits_kernel<<<dim3(Lq / 256, 64), blk, 0, stream>>>(B2, qp, score);
    softmax4097_kernel<<<64, blk, 0, stream>>>(score);

    // 3) phiK = tanh(K@Wfk+bfk)+1 -> PK ; phiQ -> PQ
    mfma_gemm<1, false, false, true, true><<<g_gemm, blk, 0, stream>>>(
        B2, Dm, Wtfk, Dm, bfk, PK, nullptr, nullptr, Mrows, Dm, Dm);
    mfma_gemm<1, false, false, true, true><<<g_gemm, blk, 0, stream>>>(
        B1, Dm, Wtfq, Dm, bfq, PQ, nullptr, nullptr, Mrows, Dm, Dm);

    // 4) V = LN(x@Wv+bv) -> B1 (Q dead; xb B0 dead afterwards)
    mfma_gemm<0, false, false, true, true><<<g_gemm, blk, 0, stream>>>(
        B0, Dm, Wtv, Dm, bv, B1, nullptr, nullptr, Mrows, Dm, Dm);
    ln1024_bf16_kernel<<<Mrows, blk, 0, stream>>>(B1, B1, gv, betav);

    // 5) KV / Ksum
    kv_kernel<<<dim3(8, 64), blk, 0, stream>>>(PK, B1, score, KV);
    ksum_kernel<<<dim3(8, 64), dim3(64), 0, stream>>>(PK, score, bfk, Ksum);

    // 6) attention out -> B2, attn LN -> a (in B2)
    attnout_kernel<<<Mrows, blk, 0, stream>>>(PQ, KV, Ksum, B2);
    ln1024_bf16_kernel<<<Mrows, blk, 0, stream>>>(B2, B2, ga, ba);

    // 7) MLP, 4 chunks of 1024 hidden: h1c = gelu(a@W1c+b1c) -> B0,
    //    out (+)= h1c @ W2c; c0 adds b2, c3 adds residuals a + x (fp32 out)
    for (int c = 0; c < 4; ++c) {
        mfma_gemm<2, false, false, true, true><<<g_gemm, blk, 0, stream>>>(
            B2, Dm, Wt1 + (size_t)c * 1024 * Dm, Dm, b1 + c * 1024,
            B0, nullptr, nullptr, Mrows, Dm, Dm);
        if (c == 0) {
            mfma_gemm<0, false, false, true, false><<<g_gemm, blk, 0, stream>>>(
                B0, Dm, Wt2 + (size_t)c * 1024, Dmlp, b2,
                outp, nullptr, nullptr, Mrows, Dm, Dm);
        } else if (c < 3) {
            mfma_gemm<0, false, true, false, false><<<g_gemm, blk, 0, stream>>>(
                B0, Dm, Wt2 + (size_t)c * 1024, Dmlp, nullptr,
                outp, nullptr, nullptr, Mrows, Dm, Dm);
        } else {
            mfma_gemm<0, true, true, false, false><<<g_gemm, blk, 0, stream>>>(
                B0, Dm, Wt2 + (size_t)c * 1024, Dmlp, nullptr,
                outp, B2, x, Mrows, Dm, Dm);
        }
    }
}

// Round 4
// 986.407 us; speedup vs baseline: 5.6235x; 1.1143x over previous
//
#include <hip/hip_runtime.h>
#include <cstddef>
#include <cstdint>

static constexpr int Bc   = 4;
static constexpr int Lq   = 4096;
static constexpr int Dm   = 1024;
static constexpr int Dmlp = 4096;
static constexpr int Mrows = Bc * Lq;   // 16384
static constexpr int Lk1   = Lq + 1;    // 4097

typedef unsigned short u16;
typedef __bf16 bf16_t;
typedef bf16_t bf16x8 __attribute__((ext_vector_type(8)));
typedef float  f32x4  __attribute__((ext_vector_type(4)));

__device__ __forceinline__ u16 f2b(float f) {
    uint32_t u = __builtin_bit_cast(uint32_t, f);
    return (u16)((u + 0x7FFFu + ((u >> 16) & 1u)) >> 16);
}
__device__ __forceinline__ float b2f(u16 h) {
    uint32_t u = ((uint32_t)h) << 16;
    return __builtin_bit_cast(float, u);
}

#define GLL16(gsrc, ldst) \
    __builtin_amdgcn_global_load_lds( \
        (const __attribute__((address_space(1))) void*)(gsrc), \
        (__attribute__((address_space(3))) void*)(ldst), 16, 0, 0)

// ---------------------------------------------------------------------------
// zero fill
// ---------------------------------------------------------------------------
__global__ __launch_bounds__(256)
void zero_kernel(float* __restrict__ p, int n) {
    const int i = blockIdx.x * 256 + threadIdx.x;
    if (i < n) p[i] = 0.0f;
}

// ---------------------------------------------------------------------------
// fp32 -> bf16 elementwise convert (x -> xb), vectorized
// ---------------------------------------------------------------------------
__global__ __launch_bounds__(256)
void cvt_bf16_kernel(const float* __restrict__ in, u16* __restrict__ outp, int n) {
    for (int i = (blockIdx.x * 256 + threadIdx.x) * 4; i < n; i += gridDim.x * 256 * 4) {
        float4 v = *(const float4*)&in[i];
        ushort4 o = { f2b(v.x), f2b(v.y), f2b(v.z), f2b(v.w) };
        *(ushort4*)&outp[i] = o;
    }
}

// ---------------------------------------------------------------------------
// W [R][C] fp32  ->  Wt [C][R] bf16, 64x64 LDS tile
// ---------------------------------------------------------------------------
__global__ __launch_bounds__(256)
void transpose_bf16_kernel(const float* __restrict__ in, u16* __restrict__ outp,
                           int R, int C) {
    __shared__ float tile[64][65];
    const int r0 = blockIdx.y * 64, c0 = blockIdx.x * 64;
    const int t = threadIdx.x;
    const int lr = t >> 2, lc0 = (t & 3) * 16;
    #pragma unroll
    for (int j = 0; j < 4; ++j) {
        float4 v = *(const float4*)&in[(size_t)(r0 + lr) * C + c0 + lc0 + j * 4];
        tile[lr][lc0 + j * 4 + 0] = v.x;
        tile[lr][lc0 + j * 4 + 1] = v.y;
        tile[lr][lc0 + j * 4 + 2] = v.z;
        tile[lr][lc0 + j * 4 + 3] = v.w;
    }
    __syncthreads();
    const int oc = t >> 2, rr0 = (t & 3) * 16;
    union { u16 u[16]; uint4 v[2]; } pk;
    #pragma unroll
    for (int j = 0; j < 16; ++j) pk.u[j] = f2b(tile[rr0 + j][oc]);
    u16* po = &outp[(size_t)(c0 + oc) * R + r0 + rr0];
    *(uint4*)&po[0] = pk.v[0];
    *(uint4*)&po[8] = pk.v[1];
}

// ---------------------------------------------------------------------------
// MFMA bf16 GEMM: C[M,N] = act(A[M,K] @ Wt[N,K]^T (+bias)) (+C)(+res1+res2)
// 128x128 tile, BK=32, 4 waves (2x2), 16x16x32 MFMA, global_load_lds staging.
// ACT: 0 none, 1 tanh+1, 2 exact GELU. OBF16: write bf16, else fp32.
// ---------------------------------------------------------------------------
template<int ACT, bool RES, bool ACCUM, bool BIAS, bool OBF16>
__global__ __launch_bounds__(256, 2)
void mfma_gemm(const u16* __restrict__ A, int ldA,
               const u16* __restrict__ Bt, int ldB,
               const float* __restrict__ bias,
               void* __restrict__ Cout,
               const u16* __restrict__ res1, const float* __restrict__ res2,
               int M, int N, int K) {
    __shared__ u16 As[4096];   // [128][32]
    __shared__ u16 Bs[4096];   // [128][32]
    const int tid  = threadIdx.x;
    const int brow = blockIdx.y * 128;
    const int bcol = blockIdx.x * 128;
    const int l   = tid & 63;
    const int w   = tid >> 6;
    const int wr  = (w >> 1) * 64;
    const int wc  = (w & 1) * 64;
    const int l16 = l & 15, l4 = l >> 4;

    const u16* ga = A  + (size_t)(brow + (tid >> 2)) * ldA + (tid & 3) * 8;
    const u16* gb = Bt + (size_t)(bcol + (tid >> 2)) * ldB + (tid & 3) * 8;
    const size_t gsA = (size_t)64 * ldA;
    const size_t gsB = (size_t)64 * ldB;
    u16* lA = As + tid * 8;
    u16* lB = Bs + tid * 8;

    f32x4 acc[4][4];
    const f32x4 zf = {0.f, 0.f, 0.f, 0.f};
    #pragma unroll
    for (int m = 0; m < 4; ++m)
        #pragma unroll
        for (int n = 0; n < 4; ++n) acc[m][n] = zf;

    const int aoff = (wr + l16) * 32 + l4 * 8;   // + m*512
    const int boff = (wc + l16) * 32 + l4 * 8;   // + n*512

    for (int k0 = 0; k0 < K; k0 += 32) {
        GLL16(ga,       lA);
        GLL16(ga + gsA, lA + 2048);
        GLL16(gb,       lB);
        GLL16(gb + gsB, lB + 2048);
        ga += 32; gb += 32;
        __syncthreads();               // drains vmcnt(0) + barrier
        bf16x8 af[4], bfv[4];
        #pragma unroll
        for (int m = 0; m < 4; ++m) af[m]  = *(const bf16x8*)&As[aoff + m * 512];
        #pragma unroll
        for (int n = 0; n < 4; ++n) bfv[n] = *(const bf16x8*)&Bs[boff + n * 512];
        #pragma unroll
        for (int m = 0; m < 4; ++m)
            #pragma unroll
            for (int n = 0; n < 4; ++n)
                acc[m][n] = __builtin_amdgcn_mfma_f32_16x16x32_bf16(
                    af[m], bfv[n], acc[m][n], 0, 0, 0);
        __syncthreads();
    }

    float bvn[4];
    #pragma unroll
    for (int n = 0; n < 4; ++n)
        bvn[n] = BIAS ? bias[bcol + wc + n * 16 + l16] : 0.f;

    #pragma unroll
    for (int m = 0; m < 4; ++m) {
        #pragma unroll
        for (int q = 0; q < 4; ++q) {
            const size_t row = (size_t)brow + wr + m * 16 + l4 * 4 + q;
            #pragma unroll
            for (int n = 0; n < 4; ++n) {
                const size_t col = (size_t)bcol + wc + n * 16 + l16;
                float v = acc[m][n][q] + bvn[n];
                if (ACT == 1) v = tanhf(v) + 1.0f;
                if (ACT == 2) v = 0.5f * v * (1.0f + erff(v * 0.70710678118654752f));
                const size_t idx = row * (size_t)N + col;
                if (OBF16) {
                    ((u16*)Cout)[idx] = f2b(v);
                } else {
                    float* Cf = (float*)Cout;
                    if (ACCUM) v += Cf[idx];
                    if (RES)   v += b2f(res1[idx]) + res2[idx];
                    Cf[idx] = v;
                }
            }
        }
    }
}

// ---------------------------------------------------------------------------
// LayerNorm(1024) on bf16, in-place safe
// ---------------------------------------------------------------------------
__global__ __launch_bounds__(256)
void ln1024_bf16_kernel(const u16* __restrict__ in, u16* __restrict__ outp,
                        const float* __restrict__ g, const float* __restrict__ be) {
    const size_t base = (size_t)blockIdx.x * Dm;
    const int tid = threadIdx.x;
    ushort4 raw = *(const ushort4*)&in[base + tid * 4];
    float v0 = b2f(raw.x), v1 = b2f(raw.y), v2 = b2f(raw.z), v3 = b2f(raw.w);
    float s  = v0 + v1 + v2 + v3;
    float sq = v0 * v0 + v1 * v1 + v2 * v2 + v3 * v3;
    #pragma unroll
    for (int off = 32; off > 0; off >>= 1) {
        s  += __shfl_down(s,  off, 64);
        sq += __shfl_down(sq, off, 64);
    }
    __shared__ float rs[4], rq[4];
    const int lane = tid & 63, wv = tid >> 6;
    if (lane == 0) { rs[wv] = s; rq[wv] = sq; }
    __syncthreads();
    s  = rs[0] + rs[1] + rs[2] + rs[3];
    sq = rq[0] + rq[1] + rq[2] + rq[3];
    const float mean = s * (1.0f / 1024.0f);
    const float var  = sq * (1.0f / 1024.0f) - mean * mean;
    const float inv  = rsqrtf(var + 1e-5f);
    float4 gv = *(const float4*)&g[tid * 4];
    float4 bv = *(const float4*)&be[tid * 4];
    ushort4 o;
    o.x = f2b((v0 - mean) * inv * gv.x + bv.x);
    o.y = f2b((v1 - mean) * inv * gv.y + bv.y);
    o.z = f2b((v2 - mean) * inv * gv.z + bv.z);
    o.w = f2b((v3 - mean) * inv * gv.w + bv.w);
    *(ushort4*)&outp[base + tid * 4] = o;
}

// ---------------------------------------------------------------------------
// q_probe[b,c] = (1/(L*sqrt(64))) * sum_l Q[b,l,c]   (Q bf16)
// ---------------------------------------------------------------------------
__global__ __launch_bounds__(256)
void qprobe_kernel(const u16* __restrict__ Q, float* __restrict__ qp) {
    const int b = blockIdx.z;
    const int col = blockIdx.x * 256 + threadIdx.x;
    const int lchunk = Lq / 16;
    const int l0 = blockIdx.y * lchunk;
    const u16* p = Q + ((size_t)b * Lq + l0) * Dm + col;
    float s = 0.f;
    for (int l = 0; l < lchunk; ++l, p += Dm) s += b2f(*p);
    atomicAdd(&qp[b * Dm + col], s * (1.0f / (4096.0f * 8.0f)));
}

// ---------------------------------------------------------------------------
// logits[bh,k] = q_probe . K row (bf16); token 0 logit = 0
// ---------------------------------------------------------------------------
__global__ __launch_bounds__(256)
void logits_kernel(const u16* __restrict__ Kc, const float* __restrict__ qp,
                   float* __restrict__ score) {
    const int bh = blockIdx.y, b = bh >> 4, h = bh & 15;
    __shared__ float q[64];
    if (threadIdx.x < 64) q[threadIdx.x] = qp[b * Dm + h * 64 + threadIdx.x];
    __syncthreads();
    const int kr = blockIdx.x * 256 + threadIdx.x;
    const ushort4* krp = (const ushort4*)&Kc[((size_t)b * Lq + kr) * Dm + h * 64];
    float s = 0.f;
    #pragma unroll
    for (int i = 0; i < 16; ++i) {
        ushort4 v = krp[i];
        s += q[i * 4 + 0] * b2f(v.x) + q[i * 4 + 1] * b2f(v.y)
           + q[i * 4 + 2] * b2f(v.z) + q[i * 4 + 3] * b2f(v.w);
    }
    score[(size_t)bh * Lk1 + kr + 1] = s;
    if (blockIdx.x == 0 && threadIdx.x == 0) score[(size_t)bh * Lk1] = 0.f;
}

// ---------------------------------------------------------------------------
// softmax over 4097, one block per (b,h)
// ---------------------------------------------------------------------------
__global__ __launch_bounds__(256)
void softmax4097_kernel(float* __restrict__ sc) {
    __shared__ float buf[Lk1];
    __shared__ float red[8];
    const size_t base = (size_t)blockIdx.x * Lk1;
    const int tid = threadIdx.x;
    float mx = -1e30f;
    for (int i = tid; i < Lk1; i += 256) { float v = sc[base + i]; buf[i] = v; mx = fmaxf(mx, v); }
    #pragma unroll
    for (int off = 32; off > 0; off >>= 1) mx = fmaxf(mx, __shfl_down(mx, off, 64));
    const int lane = tid & 63, wv = tid >> 6;
    if (lane == 0) red[wv] = mx;
    __syncthreads();
    mx = fmaxf(fmaxf(red[0], red[1]), fmaxf(red[2], red[3]));
    float sum = 0.f;
    for (int i = tid; i < Lk1; i += 256) { float e = expf(buf[i] - mx); buf[i] = e; sum += e; }
    #pragma unroll
    for (int off = 32; off > 0; off >>= 1) sum += __shfl_down(sum, off, 64);
    if (lane == 0) red[4 + wv] = sum;
    __syncthreads();
    sum = red[4] + red[5] + red[6] + red[7];
    const float inv = 1.0f / sum;
    for (int i = tid; i < Lk1; i += 256) sc[base + i] = buf[i] * inv;
}

// ---------------------------------------------------------------------------
// KV[b,h,d,e] += sum_l (score[l+1]*phiK[l,d]) * V[l,e]   (bf16 inputs)
// ---------------------------------------------------------------------------
__global__ __launch_bounds__(256)
void kv_kernel(const u16* __restrict__ phiK, const u16* __restrict__ Vc,
               const float* __restrict__ sc, float* __restrict__ KV) {
    const int bh = blockIdx.y, b = bh >> 4, h = bh & 15;
    const int lchunk = Lq / 8;
    const int l0 = blockIdx.x * lchunk;
    __shared__ float pk[8][64];
    __shared__ float vv[8][64];
    const int i0 = (threadIdx.x >> 4) << 2;
    const int j0 = (threadIdx.x & 15) << 2;
    float acc[4][4] = {};
    for (int lb = l0; lb < l0 + lchunk; lb += 8) {
        #pragma unroll
        for (int q = 0; q < 2; ++q) {
            const int idx = threadIdx.x + q * 256;
            const int r = idx >> 6, c = idx & 63;
            const float scv = sc[(size_t)bh * Lk1 + lb + r + 1];
            const size_t off = ((size_t)b * Lq + lb + r) * Dm + h * 64 + c;
            pk[r][c] = b2f(phiK[off]) * scv;
            vv[r][c] = b2f(Vc[off]);
        }
        __syncthreads();
        #pragma unroll
        for (int r = 0; r < 8; ++r) {
            float ra[4], rb[4];
            #pragma unroll
            for (int i = 0; i < 4; ++i) ra[i] = pk[r][i0 + i];
            #pragma unroll
            for (int j = 0; j < 4; ++j) rb[j] = vv[r][j0 + j];
            #pragma unroll
            for (int i = 0; i < 4; ++i)
                #pragma unroll
                for (int j = 0; j < 4; ++j)
                    acc[i][j] = fmaf(ra[i], rb[j], acc[i][j]);
        }
        __syncthreads();
    }
    #pragma unroll
    for (int i = 0; i < 4; ++i)
        #pragma unroll
        for (int j = 0; j < 4; ++j)
            atomicAdd(&KV[((size_t)bh * 64 + i0 + i) * 64 + j0 + j], acc[i][j]);
}

// ---------------------------------------------------------------------------
// Ksum[b,h,d] = sum_k score[k]*phiK[k,d] incl. zero token tanh(bfk)+1
// ---------------------------------------------------------------------------
__global__ __launch_bounds__(64)
void ksum_kernel(const u16* __restrict__ phiK, const float* __restrict__ sc,
                 const float* __restrict__ bfk, float* __restrict__ Ksum) {
    const int bh = blockIdx.y, b = bh >> 4, h = bh & 15;
    const int lchunk = Lq / 8;
    const int l0 = blockIdx.x * lchunk;
    const int dd = threadIdx.x;
    float s = 0.f;
    const u16* pp = &phiK[((size_t)b * Lq + l0) * Dm + h * 64 + dd];
    const float* sp = &sc[(size_t)bh * Lk1 + l0 + 1];
    for (int l = 0; l < lchunk; ++l, pp += Dm) s = fmaf(b2f(*pp), sp[l], s);
    if (blockIdx.x == 0) s += sc[(size_t)bh * Lk1] * (tanhf(bfk[h * 64 + dd]) + 1.0f);
    atomicAdd(&Ksum[bh * 64 + dd], s);
}

// ---------------------------------------------------------------------------
// out = (phiQ @ KV) / (phiQ . Ksum + 1e-6), bf16 in/out.
// One block per (b,h, 64-row tile): KV head + pq tile + Ksum staged in LDS,
// per-row 1/den precomputed (conflict-free via [64][65] pad). Main loop:
// pqs broadcast x kvs stride-1 -> conflict-free, no global loads.
// ---------------------------------------------------------------------------
__global__ __launch_bounds__(256)
void attnout_kernel(const u16* __restrict__ phiQ, const float* __restrict__ KV,
                    const float* __restrict__ Ksum, u16* __restrict__ outp) {
    const int bh = blockIdx.y, b = bh >> 4, h = bh & 15;
    const int l0 = blockIdx.x * 64;
    __shared__ float kvs[64][64];   // kvs[d][e]
    __shared__ float pqs[64][65];   // pqs[row][d], padded
    __shared__ float kss[64];
    __shared__ float dns[64];
    const int tid = threadIdx.x;

    // stage KV head (4096 floats, coalesced float4)
    {
        const float* kvg = &KV[(size_t)bh * 4096];
        float* kf = &kvs[0][0];
        #pragma unroll
        for (int j = 0; j < 4; ++j)
            *(float4*)&kf[tid * 16 + j * 4] = *(const float4*)&kvg[tid * 16 + j * 4];
    }
    if (tid < 64) kss[tid] = Ksum[bh * 64 + tid];
    // stage pq tile: row = tid>>2, 16 cols per thread
    {
        const int row = tid >> 2, c0 = (tid & 3) * 16;
        const u16* pg = &phiQ[((size_t)(b * Lq + l0 + row)) * Dm + h * 64 + c0];
        #pragma unroll
        for (int j = 0; j < 4; ++j) {
            ushort4 u = *(const ushort4*)&pg[j * 4];
            pqs[row][c0 + j * 4 + 0] = b2f(u.x);
            pqs[row][c0 + j * 4 + 1] = b2f(u.y);
            pqs[row][c0 + j * 4 + 2] = b2f(u.z);
            pqs[row][c0 + j * 4 + 3] = b2f(u.w);
        }
    }
    __syncthreads();
    if (tid < 64) {
        float s = 0.f;
        #pragma unroll
        for (int d = 0; d < 64; ++d) s = fmaf(pqs[tid][d], kss[d], s);
        dns[tid] = 1.0f / (s + 1e-6f);
    }
    __syncthreads();

    const int e = tid & 63;
    const int rg = tid >> 6;     // 0..3
    #pragma unroll 2
    for (int p = 0; p < 16; ++p) {
        const int row = p * 4 + rg;
        float acc = 0.f;
        #pragma unroll
        for (int d = 0; d < 64; ++d)
            acc = fmaf(pqs[row][d], kvs[d][e], acc);
        outp[(((size_t)(b * Lq + l0 + row)) << 10) + h * 64 + e] = f2b(acc * dns[row]);
    }
}

// ---------------------------------------------------------------------------
extern "C" void kernel_launch(void* const* d_in, const int* in_sizes, int n_in,
                              void* d_out, int out_size, void* d_ws, size_t ws_size,
                              hipStream_t stream) {
    const float* x     = (const float*)d_in[0];
    const float* Wq    = (const float*)d_in[1];
    const float* bq    = (const float*)d_in[2];
    const float* gq    = (const float*)d_in[3];
    const float* betaq = (const float*)d_in[4];
    const float* Wk    = (const float*)d_in[5];
    const float* bk    = (const float*)d_in[6];
    const float* gk    = (const float*)d_in[7];
    const float* betak = (const float*)d_in[8];
    const float* Wv    = (const float*)d_in[9];
    const float* bv    = (const float*)d_in[10];
    const float* gv    = (const float*)d_in[11];
    const float* betav = (const float*)d_in[12];
    const float* Wfq   = (const float*)d_in[13];
    const float* bfq   = (const float*)d_in[14];
    const float* Wfk   = (const float*)d_in[15];
    const float* bfk   = (const float*)d_in[16];
    const float* ga    = (const float*)d_in[17];
    const float* ba    = (const float*)d_in[18];
    const float* W1    = (const float*)d_in[19];
    const float* b1    = (const float*)d_in[20];
    const float* W2    = (const float*)d_in[21];
    const float* b2    = (const float*)d_in[22];
    float* outp = (float*)d_out;

    // ---- workspace layout (~124 MB) ----
    uint8_t* wsb = (uint8_t*)d_ws;
    size_t off = 0;
    auto alloc = [&](size_t bytes) { void* p = wsb + off; off += bytes; return p; };
    const size_t Md = (size_t)Mrows * Dm;   // 16,777,216
    u16* B0   = (u16*)alloc(Md * 2);        // xb -> h1-chunk (with B1)
    u16* B1   = (u16*)alloc(Md * 2);        // Q_ln -> V_ln -> h1-chunk tail
    u16* B2   = (u16*)alloc(Md * 2);        // K_ln -> attn_out/a
    u16* Wtq  = (u16*)alloc((size_t)Dm * Dm * 2);
    u16* Wtk  = (u16*)alloc((size_t)Dm * Dm * 2);
    u16* Wtv  = (u16*)alloc((size_t)Dm * Dm * 2);
    u16* Wtfq = (u16*)alloc((size_t)Dm * Dm * 2);
    u16* Wtfk = (u16*)alloc((size_t)Dm * Dm * 2);
    u16* Wt1  = (u16*)alloc((size_t)Dm * Dmlp * 2);   // [4096][1024]
    u16* Wt2  = (u16*)alloc((size_t)Dm * Dmlp * 2);   // [1024][4096]
    float* qp    = (float*)alloc(4096 * 4);
    float* KV    = (float*)alloc((size_t)64 * 64 * 64 * 4);
    float* Ksum  = (float*)alloc(4096 * 4);
    float* score = (float*)alloc((size_t)64 * Lk1 * 4);
    u16* PK = (u16*)outp;        // borrow d_out (bf16): first half
    u16* PQ = (u16*)outp + Md;   // second half

    const dim3 blk(256);
    const dim3 g_gemm(8, 128);       // N=1024
    const dim3 g_gemm2k(16, 128);    // N=2048

    // 0) converts + transposes
    cvt_bf16_kernel<<<2048, blk, 0, stream>>>(x, B0, (int)Md);
    transpose_bf16_kernel<<<dim3(16, 16), blk, 0, stream>>>(Wq,  Wtq,  Dm, Dm);
    transpose_bf16_kernel<<<dim3(16, 16), blk, 0, stream>>>(Wk,  Wtk,  Dm, Dm);
    transpose_bf16_kernel<<<dim3(16, 16), blk, 0, stream>>>(Wv,  Wtv,  Dm, Dm);
    transpose_bf16_kernel<<<dim3(16, 16), blk, 0, stream>>>(Wfq, Wtfq, Dm, Dm);
    transpose_bf16_kernel<<<dim3(16, 16), blk, 0, stream>>>(Wfk, Wtfk, Dm, Dm);
    transpose_bf16_kernel<<<dim3(64, 16), blk, 0, stream>>>(W1,  Wt1,  Dm, Dmlp);
    transpose_bf16_kernel<<<dim3(16, 64), blk, 0, stream>>>(W2,  Wt2,  Dmlp, Dm);
    {   // zero qp + KV + Ksum (contiguous)
        const int nz = 4096 + 64 * 64 * 64 + 4096;
        zero_kernel<<<(nz + 255) / 256, blk, 0, stream>>>(qp, nz);
    }

    // 1) Q = LN(x@Wq+bq) -> B1 ; K = LN(x@Wk+bk) -> B2
    mfma_gemm<0, false, false, true, true><<<g_gemm, blk, 0, stream>>>(
        B0, Dm, Wtq, Dm, bq, B1, nullptr, nullptr, Mrows, Dm, Dm);
    ln1024_bf16_kernel<<<Mrows, blk, 0, stream>>>(B1, B1, gq, betaq);
    mfma_gemm<0, false, false, true, true><<<g_gemm, blk, 0, stream>>>(
        B0, Dm, Wtk, Dm, bk, B2, nullptr, nullptr, Mrows, Dm, Dm);
    ln1024_bf16_kernel<<<Mrows, blk, 0, stream>>>(B2, B2, gk, betak);

    // 2) probe softmax gating
    qprobe_kernel<<<dim3(Dm / 256, 16, Bc), blk, 0, stream>>>(B1, qp);
    logits_kernel<<<dim3(Lq / 256, 64), blk, 0, stream>>>(B2, qp, score);
    softmax4097_kernel<<<64, blk, 0, stream>>>(score);

    // 3) phiK = tanh(K@Wfk+bfk)+1 -> PK ; phiQ -> PQ
    mfma_gemm<1, false, false, true, true><<<g_gemm, blk, 0, stream>>>(
        B2, Dm, Wtfk, Dm, bfk, PK, nullptr, nullptr, Mrows, Dm, Dm);
    mfma_gemm<1, false, false, true, true><<<g_gemm, blk, 0, stream>>>(
        B1, Dm, Wtfq, Dm, bfq, PQ, nullptr, nullptr, Mrows, Dm, Dm);

    // 4) V = LN(x@Wv+bv) -> B1 (Q dead; xb in B0 dead afterwards)
    mfma_gemm<0, false, false, true, true><<<g_gemm, blk, 0, stream>>>(
        B0, Dm, Wtv, Dm, bv, B1, nullptr, nullptr, Mrows, Dm, Dm);
    ln1024_bf16_kernel<<<Mrows, blk, 0, stream>>>(B1, B1, gv, betav);

    // 5) KV / Ksum
    kv_kernel<<<dim3(8, 64), blk, 0, stream>>>(PK, B1, score, KV);
    ksum_kernel<<<dim3(8, 64), dim3(64), 0, stream>>>(PK, score, bfk, Ksum);

    // 6) attention out -> B2, attn LN -> a (in B2)
    attnout_kernel<<<dim3(Lq / 64, 64), blk, 0, stream>>>(PQ, KV, Ksum, B2);
    ln1024_bf16_kernel<<<Mrows, blk, 0, stream>>>(B2, B2, ga, ba);

    // 7) MLP, 2 chunks of 2048 hidden. h1c [16384][2048] bf16 = 64 MB
    //    overlays B0+B1 (both dead). c0: out = h1c@W2c + b2;
    //    c1: out += h1c@W2c + a + x (fp32 out).
    u16* H1 = B0;
    for (int c = 0; c < 2; ++c) {
        mfma_gemm<2, false, false, true, true><<<g_gemm2k, blk, 0, stream>>>(
            B2, Dm, Wt1 + (size_t)c * 2048 * Dm, Dm, b1 + c * 2048,
            H1, nullptr, nullptr, Mrows, 2048, Dm);
        if (c == 0) {
            mfma_gemm<0, false, false, true, false><<<g_gemm, blk, 0, stream>>>(
                H1, 2048, Wt2 + (size_t)c * 2048, Dmlp, b2,
                outp, nullptr, nullptr, Mrows, Dm, 2048);
        } else {
            mfma_gemm<0, true, true, false, false><<<g_gemm, blk, 0, stream>>>(
                H1, 2048, Wt2 + (size_t)c * 2048, Dmlp, nullptr,
                outp, B2, x, Mrows, Dm, 2048);
        }
    }
}

// Round 5
// 876.250 us; speedup vs baseline: 6.3305x; 1.1257x over previous
//
#include <hip/hip_runtime.h>
#include <cstddef>
#include <cstdint>

static constexpr int Bc   = 4;
static constexpr int Lq   = 4096;
static constexpr int Dm   = 1024;
static constexpr int Dmlp = 4096;
static constexpr int Mrows = Bc * Lq;   // 16384
static constexpr int Lk1   = Lq + 1;    // 4097

typedef unsigned short u16;
typedef __bf16 bf16_t;
typedef bf16_t bf16x8 __attribute__((ext_vector_type(8)));
typedef float  f32x4  __attribute__((ext_vector_type(4)));

__device__ __forceinline__ u16 f2b(float f) {
    uint32_t u = __builtin_bit_cast(uint32_t, f);
    return (u16)((u + 0x7FFFu + ((u >> 16) & 1u)) >> 16);
}
__device__ __forceinline__ float b2f(u16 h) {
    uint32_t u = ((uint32_t)h) << 16;
    return __builtin_bit_cast(float, u);
}

#define GLL16(gsrc, ldst) \
    __builtin_amdgcn_global_load_lds( \
        (const __attribute__((address_space(1))) void*)(gsrc), \
        (__attribute__((address_space(3))) void*)(ldst), 16, 0, 0)

// ---------------------------------------------------------------------------
__global__ __launch_bounds__(256)
void zero_kernel(float* __restrict__ p, int n) {
    const int i = blockIdx.x * 256 + threadIdx.x;
    if (i < n) p[i] = 0.0f;
}

__global__ __launch_bounds__(256)
void cvt_bf16_kernel(const float* __restrict__ in, u16* __restrict__ outp, int n) {
    for (int i = (blockIdx.x * 256 + threadIdx.x) * 4; i < n; i += gridDim.x * 256 * 4) {
        float4 v = *(const float4*)&in[i];
        ushort4 o = { f2b(v.x), f2b(v.y), f2b(v.z), f2b(v.w) };
        *(ushort4*)&outp[i] = o;
    }
}

// W [R][C] fp32 -> Wt [C][R] bf16
__global__ __launch_bounds__(256)
void transpose_bf16_kernel(const float* __restrict__ in, u16* __restrict__ outp,
                           int R, int C) {
    __shared__ float tile[64][65];
    const int r0 = blockIdx.y * 64, c0 = blockIdx.x * 64;
    const int t = threadIdx.x;
    const int lr = t >> 2, lc0 = (t & 3) * 16;
    #pragma unroll
    for (int j = 0; j < 4; ++j) {
        float4 v = *(const float4*)&in[(size_t)(r0 + lr) * C + c0 + lc0 + j * 4];
        tile[lr][lc0 + j * 4 + 0] = v.x;
        tile[lr][lc0 + j * 4 + 1] = v.y;
        tile[lr][lc0 + j * 4 + 2] = v.z;
        tile[lr][lc0 + j * 4 + 3] = v.w;
    }
    __syncthreads();
    const int oc = t >> 2, rr0 = (t & 3) * 16;
    union { u16 u[16]; uint4 v[2]; } pk;
    #pragma unroll
    for (int j = 0; j < 16; ++j) pk.u[j] = f2b(tile[rr0 + j][oc]);
    u16* po = &outp[(size_t)(c0 + oc) * R + r0 + rr0];
    *(uint4*)&po[0] = pk.v[0];
    *(uint4*)&po[8] = pk.v[1];
}

// ---------------------------------------------------------------------------
// 256x256 MFMA GEMM, BK=32, ring-4 LDS (128 KiB), counted vmcnt, T2 swizzle,
// XCD block swizzle, setprio. 8 waves (2M x 4N), per-wave 128x64 out.
// C[M,N] = act(A[M,K] @ Bt[N,K]^T (+bias)) (+C)(+res1+res2)
// ---------------------------------------------------------------------------
template<int ACT, bool RES, bool ACCUM, bool BIAS, bool OBF16>
__global__ __launch_bounds__(512, 1)
void mfma_gemm256(const u16* __restrict__ A, int ldA,
                  const u16* __restrict__ Bt, int ldB,
                  const float* __restrict__ bias,
                  void* __restrict__ Cout,
                  const u16* __restrict__ res1, const float* __restrict__ res2,
                  int M, int N, int K) {
    __shared__ u16 ldsA[4][8192];   // 4 x 16 KiB  [256 rows][32 k] swizzled
    __shared__ u16 ldsB[4][8192];   // 4 x 16 KiB
    const int tid = threadIdx.x;
    const int l   = tid & 63;
    const int w   = tid >> 6;        // 0..7
    const int wm  = w >> 2;          // 0..1 (M half)
    const int wn  = w & 3;           // 0..3 (N quarter)
    const int l16 = l & 15, l4 = l >> 4;

    // XCD-aware bijective block swizzle (nwg % 8 == 0 for all our shapes)
    const int gx = N >> 8;
    int bid = blockIdx.x;
    bid = (bid & 7) * ((int)gridDim.x >> 3) + (bid >> 3);
    const int brow = (bid / gx) << 8;
    const int bcol = (bid % gx) << 8;

    // --- staging addresses (global source pre-swizzled; LDS dest linear) ---
    // issue j: row = j*128 + w*16 + (l>>2); k-slot16 swizzle ^((row>>1)&3) = ^((l>>3)&3)
    const int srow = w * 16 + (l >> 2);
    const int skof = ((l & 3) ^ ((l >> 3) & 3)) << 3;    // k element offset
    const u16* gA = A  + (size_t)(brow + srow) * ldA + skof;
    const u16* gB = Bt + (size_t)(bcol + srow) * ldB + skof;
    const size_t gsA = (size_t)128 * ldA;
    const size_t gsB = (size_t)128 * ldB;
    const int ldst = w * 512 + l * 8;   // u16 offset within slot (+4096 for j=1)

    // --- swizzled ds_read fragment offsets ---
    // A frag m: row = wm*128 + m*16 + l16, kslot16' = l4 ^ ((l16>>1)&3)
    const int koff_rd = ((l4 ^ ((l16 >> 1) & 3)) << 3);
    const int aRdBase = (wm * 128 + l16) * 32 + koff_rd;   // + m*512
    const int bRdBase = (wn * 64  + l16) * 32 + koff_rd;   // + n*512

    f32x4 acc[8][4];
    const f32x4 zf = {0.f, 0.f, 0.f, 0.f};
    #pragma unroll
    for (int m = 0; m < 8; ++m)
        #pragma unroll
        for (int n = 0; n < 4; ++n) acc[m][n] = zf;

    auto stageA = [&](int slot, int kelem) {
        const u16* s = gA + (size_t)kelem;
        GLL16(s,       &ldsA[slot][ldst]);
        GLL16(s + gsA, &ldsA[slot][ldst + 4096]);
    };
    auto stageB = [&](int slot, int kelem) {
        const u16* s = gB + (size_t)kelem;
        GLL16(s,       &ldsB[slot][ldst]);
        GLL16(s + gsB, &ldsB[slot][ldst + 4096]);
    };

    const int T = K >> 5;
    // prologue: stage sets 0,1,2
    stageA(0, 0);  stageB(0, 0);
    stageA(1, 32); stageB(1, 32);
    stageA(2, 64); stageB(2, 64);

    auto step = [&](int t, int waitsel, bool do_stage) {
        asm volatile("s_waitcnt lgkmcnt(0)" ::: "memory");
        if (waitsel == 0)      asm volatile("s_waitcnt vmcnt(8)" ::: "memory");
        else if (waitsel == 1) asm volatile("s_waitcnt vmcnt(4)" ::: "memory");
        else                   asm volatile("s_waitcnt vmcnt(0)" ::: "memory");
        asm volatile("s_barrier" ::: "memory");
        const int slot = t & 3;
        bf16x8 afr[4], bfr[4];
        #pragma unroll
        for (int n = 0; n < 4; ++n)
            bfr[n] = *(const bf16x8*)&ldsB[slot][bRdBase + n * 512];
        #pragma unroll
        for (int m = 0; m < 4; ++m)
            afr[m] = *(const bf16x8*)&ldsA[slot][aRdBase + m * 512];
        if (do_stage) stageA((t + 3) & 3, (t + 3) * 32);
        __builtin_amdgcn_s_setprio(1);
        #pragma unroll
        for (int m = 0; m < 4; ++m)
            #pragma unroll
            for (int n = 0; n < 4; ++n)
                acc[m][n] = __builtin_amdgcn_mfma_f32_16x16x32_bf16(
                    afr[m], bfr[n], acc[m][n], 0, 0, 0);
        __builtin_amdgcn_s_setprio(0);
        #pragma unroll
        for (int m = 0; m < 4; ++m)
            afr[m] = *(const bf16x8*)&ldsA[slot][aRdBase + (m + 4) * 512];
        if (do_stage) stageB((t + 3) & 3, (t + 3) * 32);
        __builtin_amdgcn_s_setprio(1);
        #pragma unroll
        for (int m = 0; m < 4; ++m)
            #pragma unroll
            for (int n = 0; n < 4; ++n)
                acc[m + 4][n] = __builtin_amdgcn_mfma_f32_16x16x32_bf16(
                    afr[m], bfr[n], acc[m + 4][n], 0, 0, 0);
        __builtin_amdgcn_s_setprio(0);
    };

    for (int t = 0; t < T - 2; ++t) step(t, 0, (t + 3) < T);
    step(T - 2, 1, false);
    step(T - 1, 2, false);

    // --- epilogue ---
    float bvn[4];
    int coln[4];
    #pragma unroll
    for (int n = 0; n < 4; ++n) {
        coln[n] = bcol + wn * 64 + n * 16 + l16;
        bvn[n] = BIAS ? bias[coln[n]] : 0.f;
    }
    #pragma unroll
    for (int m = 0; m < 8; ++m) {
        #pragma unroll
        for (int q = 0; q < 4; ++q) {
            const size_t row = (size_t)brow + wm * 128 + m * 16 + l4 * 4 + q;
            #pragma unroll
            for (int n = 0; n < 4; ++n) {
                float v = acc[m][n][q] + bvn[n];
                if (ACT == 1) v = tanhf(v) + 1.0f;
                if (ACT == 2) v = 0.5f * v * (1.0f + erff(v * 0.70710678118654752f));
                const size_t idx = row * (size_t)N + coln[n];
                if (OBF16) {
                    ((u16*)Cout)[idx] = f2b(v);
                } else {
                    float* Cf = (float*)Cout;
                    if (ACCUM) v += Cf[idx];
                    if (RES)   v += b2f(res1[idx]) + res2[idx];
                    Cf[idx] = v;
                }
            }
        }
    }
}

// ---------------------------------------------------------------------------
__global__ __launch_bounds__(256)
void ln1024_bf16_kernel(const u16* __restrict__ in, u16* __restrict__ outp,
                        const float* __restrict__ g, const float* __restrict__ be) {
    const size_t base = (size_t)blockIdx.x * Dm;
    const int tid = threadIdx.x;
    ushort4 raw = *(const ushort4*)&in[base + tid * 4];
    float v0 = b2f(raw.x), v1 = b2f(raw.y), v2 = b2f(raw.z), v3 = b2f(raw.w);
    float s  = v0 + v1 + v2 + v3;
    float sq = v0 * v0 + v1 * v1 + v2 * v2 + v3 * v3;
    #pragma unroll
    for (int off = 32; off > 0; off >>= 1) {
        s  += __shfl_down(s,  off, 64);
        sq += __shfl_down(sq, off, 64);
    }
    __shared__ float rs[4], rq[4];
    const int lane = tid & 63, wv = tid >> 6;
    if (lane == 0) { rs[wv] = s; rq[wv] = sq; }
    __syncthreads();
    s  = rs[0] + rs[1] + rs[2] + rs[3];
    sq = rq[0] + rq[1] + rq[2] + rq[3];
    const float mean = s * (1.0f / 1024.0f);
    const float var  = sq * (1.0f / 1024.0f) - mean * mean;
    const float inv  = rsqrtf(var + 1e-5f);
    float4 gv = *(const float4*)&g[tid * 4];
    float4 bv = *(const float4*)&be[tid * 4];
    ushort4 o;
    o.x = f2b((v0 - mean) * inv * gv.x + bv.x);
    o.y = f2b((v1 - mean) * inv * gv.y + bv.y);
    o.z = f2b((v2 - mean) * inv * gv.z + bv.z);
    o.w = f2b((v3 - mean) * inv * gv.w + bv.w);
    *(ushort4*)&outp[base + tid * 4] = o;
}

__global__ __launch_bounds__(256)
void qprobe_kernel(const u16* __restrict__ Q, float* __restrict__ qp) {
    const int b = blockIdx.z;
    const int col = blockIdx.x * 256 + threadIdx.x;
    const int lchunk = Lq / 16;
    const int l0 = blockIdx.y * lchunk;
    const u16* p = Q + ((size_t)b * Lq + l0) * Dm + col;
    float s = 0.f;
    for (int l = 0; l < lchunk; ++l, p += Dm) s += b2f(*p);
    atomicAdd(&qp[b * Dm + col], s * (1.0f / (4096.0f * 8.0f)));
}

__global__ __launch_bounds__(256)
void logits_kernel(const u16* __restrict__ Kc, const float* __restrict__ qp,
                   float* __restrict__ score) {
    const int bh = blockIdx.y, b = bh >> 4, h = bh & 15;
    __shared__ float q[64];
    if (threadIdx.x < 64) q[threadIdx.x] = qp[b * Dm + h * 64 + threadIdx.x];
    __syncthreads();
    const int kr = blockIdx.x * 256 + threadIdx.x;
    const ushort4* krp = (const ushort4*)&Kc[((size_t)b * Lq + kr) * Dm + h * 64];
    float s = 0.f;
    #pragma unroll
    for (int i = 0; i < 16; ++i) {
        ushort4 v = krp[i];
        s += q[i * 4 + 0] * b2f(v.x) + q[i * 4 + 1] * b2f(v.y)
           + q[i * 4 + 2] * b2f(v.z) + q[i * 4 + 3] * b2f(v.w);
    }
    score[(size_t)bh * Lk1 + kr + 1] = s;
    if (blockIdx.x == 0 && threadIdx.x == 0) score[(size_t)bh * Lk1] = 0.f;
}

__global__ __launch_bounds__(256)
void softmax4097_kernel(float* __restrict__ sc) {
    __shared__ float buf[Lk1];
    __shared__ float red[8];
    const size_t base = (size_t)blockIdx.x * Lk1;
    const int tid = threadIdx.x;
    float mx = -1e30f;
    for (int i = tid; i < Lk1; i += 256) { float v = sc[base + i]; buf[i] = v; mx = fmaxf(mx, v); }
    #pragma unroll
    for (int off = 32; off > 0; off >>= 1) mx = fmaxf(mx, __shfl_down(mx, off, 64));
    const int lane = tid & 63, wv = tid >> 6;
    if (lane == 0) red[wv] = mx;
    __syncthreads();
    mx = fmaxf(fmaxf(red[0], red[1]), fmaxf(red[2], red[3]));
    float sum = 0.f;
    for (int i = tid; i < Lk1; i += 256) { float e = expf(buf[i] - mx); buf[i] = e; sum += e; }
    #pragma unroll
    for (int off = 32; off > 0; off >>= 1) sum += __shfl_down(sum, off, 64);
    if (lane == 0) red[4 + wv] = sum;
    __syncthreads();
    sum = red[4] + red[5] + red[6] + red[7];
    const float inv = 1.0f / sum;
    for (int i = tid; i < Lk1; i += 256) sc[base + i] = buf[i] * inv;
}

__global__ __launch_bounds__(256)
void kv_kernel(const u16* __restrict__ phiK, const u16* __restrict__ Vc,
               const float* __restrict__ sc, float* __restrict__ KV) {
    const int bh = blockIdx.y, b = bh >> 4, h = bh & 15;
    const int lchunk = Lq / 8;
    const int l0 = blockIdx.x * lchunk;
    __shared__ float pk[8][64];
    __shared__ float vv[8][64];
    const int i0 = (threadIdx.x >> 4) << 2;
    const int j0 = (threadIdx.x & 15) << 2;
    float acc[4][4] = {};
    for (int lb = l0; lb < l0 + lchunk; lb += 8) {
        #pragma unroll
        for (int q = 0; q < 2; ++q) {
            const int idx = threadIdx.x + q * 256;
            const int r = idx >> 6, c = idx & 63;
            const float scv = sc[(size_t)bh * Lk1 + lb + r + 1];
            const size_t off = ((size_t)b * Lq + lb + r) * Dm + h * 64 + c;
            pk[r][c] = b2f(phiK[off]) * scv;
            vv[r][c] = b2f(Vc[off]);
        }
        __syncthreads();
        #pragma unroll
        for (int r = 0; r < 8; ++r) {
            float ra[4], rb[4];
            #pragma unroll
            for (int i = 0; i < 4; ++i) ra[i] = pk[r][i0 + i];
            #pragma unroll
            for (int j = 0; j < 4; ++j) rb[j] = vv[r][j0 + j];
            #pragma unroll
            for (int i = 0; i < 4; ++i)
                #pragma unroll
                for (int j = 0; j < 4; ++j)
                    acc[i][j] = fmaf(ra[i], rb[j], acc[i][j]);
        }
        __syncthreads();
    }
    #pragma unroll
    for (int i = 0; i < 4; ++i)
        #pragma unroll
        for (int j = 0; j < 4; ++j)
            atomicAdd(&KV[((size_t)bh * 64 + i0 + i) * 64 + j0 + j], acc[i][j]);
}

__global__ __launch_bounds__(64)
void ksum_kernel(const u16* __restrict__ phiK, const float* __restrict__ sc,
                 const float* __restrict__ bfk, float* __restrict__ Ksum) {
    const int bh = blockIdx.y, b = bh >> 4, h = bh & 15;
    const int lchunk = Lq / 8;
    const int l0 = blockIdx.x * lchunk;
    const int dd = threadIdx.x;
    float s = 0.f;
    const u16* pp = &phiK[((size_t)b * Lq + l0) * Dm + h * 64 + dd];
    const float* sp = &sc[(size_t)bh * Lk1 + l0 + 1];
    for (int l = 0; l < lchunk; ++l, pp += Dm) s = fmaf(b2f(*pp), sp[l], s);
    if (blockIdx.x == 0) s += sc[(size_t)bh * Lk1] * (tanhf(bfk[h * 64 + dd]) + 1.0f);
    atomicAdd(&Ksum[bh * 64 + dd], s);
}

__global__ __launch_bounds__(256)
void attnout_kernel(const u16* __restrict__ phiQ, const float* __restrict__ KV,
                    const float* __restrict__ Ksum, u16* __restrict__ outp) {
    const int bh = blockIdx.y, b = bh >> 4, h = bh & 15;
    const int l0 = blockIdx.x * 64;
    __shared__ float kvs[64][64];
    __shared__ float pqs[64][65];
    __shared__ float kss[64];
    __shared__ float dns[64];
    const int tid = threadIdx.x;
    {
        const float* kvg = &KV[(size_t)bh * 4096];
        float* kf = &kvs[0][0];
        #pragma unroll
        for (int j = 0; j < 4; ++j)
            *(float4*)&kf[tid * 16 + j * 4] = *(const float4*)&kvg[tid * 16 + j * 4];
    }
    if (tid < 64) kss[tid] = Ksum[bh * 64 + tid];
    {
        const int row = tid >> 2, c0 = (tid & 3) * 16;
        const u16* pg = &phiQ[((size_t)(b * Lq + l0 + row)) * Dm + h * 64 + c0];
        #pragma unroll
        for (int j = 0; j < 4; ++j) {
            ushort4 u = *(const ushort4*)&pg[j * 4];
            pqs[row][c0 + j * 4 + 0] = b2f(u.x);
            pqs[row][c0 + j * 4 + 1] = b2f(u.y);
            pqs[row][c0 + j * 4 + 2] = b2f(u.z);
            pqs[row][c0 + j * 4 + 3] = b2f(u.w);
        }
    }
    __syncthreads();
    if (tid < 64) {
        float s = 0.f;
        #pragma unroll
        for (int d = 0; d < 64; ++d) s = fmaf(pqs[tid][d], kss[d], s);
        dns[tid] = 1.0f / (s + 1e-6f);
    }
    __syncthreads();
    const int e = tid & 63;
    const int rg = tid >> 6;
    #pragma unroll 2
    for (int p = 0; p < 16; ++p) {
        const int row = p * 4 + rg;
        float acc = 0.f;
        #pragma unroll
        for (int d = 0; d < 64; ++d)
            acc = fmaf(pqs[row][d], kvs[d][e], acc);
        outp[(((size_t)(b * Lq + l0 + row)) << 10) + h * 64 + e] = f2b(acc * dns[row]);
    }
}

// ---------------------------------------------------------------------------
extern "C" void kernel_launch(void* const* d_in, const int* in_sizes, int n_in,
                              void* d_out, int out_size, void* d_ws, size_t ws_size,
                              hipStream_t stream) {
    const float* x     = (const float*)d_in[0];
    const float* Wq    = (const float*)d_in[1];
    const float* bq    = (const float*)d_in[2];
    const float* gq    = (const float*)d_in[3];
    const float* betaq = (const float*)d_in[4];
    const float* Wk    = (const float*)d_in[5];
    const float* bk    = (const float*)d_in[6];
    const float* gk    = (const float*)d_in[7];
    const float* betak = (const float*)d_in[8];
    const float* Wv    = (const float*)d_in[9];
    const float* bv    = (const float*)d_in[10];
    const float* gv    = (const float*)d_in[11];
    const float* betav = (const float*)d_in[12];
    const float* Wfq   = (const float*)d_in[13];
    const float* bfq   = (const float*)d_in[14];
    const float* Wfk   = (const float*)d_in[15];
    const float* bfk   = (const float*)d_in[16];
    const float* ga    = (const float*)d_in[17];
    const float* ba    = (const float*)d_in[18];
    const float* W1    = (const float*)d_in[19];
    const float* b1    = (const float*)d_in[20];
    const float* W2    = (const float*)d_in[21];
    const float* b2    = (const float*)d_in[22];
    float* outp = (float*)d_out;

    uint8_t* wsb = (uint8_t*)d_ws;
    size_t off = 0;
    auto alloc = [&](size_t bytes) { void* p = wsb + off; off += bytes; return p; };
    const size_t Md = (size_t)Mrows * Dm;
    u16* B0   = (u16*)alloc(Md * 2);
    u16* B1   = (u16*)alloc(Md * 2);
    u16* B2   = (u16*)alloc(Md * 2);
    u16* Wtq  = (u16*)alloc((size_t)Dm * Dm * 2);
    u16* Wtk  = (u16*)alloc((size_t)Dm * Dm * 2);
    u16* Wtv  = (u16*)alloc((size_t)Dm * Dm * 2);
    u16* Wtfq = (u16*)alloc((size_t)Dm * Dm * 2);
    u16* Wtfk = (u16*)alloc((size_t)Dm * Dm * 2);
    u16* Wt1  = (u16*)alloc((size_t)Dm * Dmlp * 2);
    u16* Wt2  = (u16*)alloc((size_t)Dm * Dmlp * 2);
    float* qp    = (float*)alloc(4096 * 4);
    float* KV    = (float*)alloc((size_t)64 * 64 * 64 * 4);
    float* Ksum  = (float*)alloc(4096 * 4);
    float* score = (float*)alloc((size_t)64 * Lk1 * 4);
    u16* PK = (u16*)outp;
    u16* PQ = (u16*)outp + Md;

    const dim3 blk(256);
    const dim3 blk512(512);
    const dim3 gA(256);   // (16384/256)*(1024/256)
    const dim3 gM(512);   // (16384/256)*(2048/256)

    cvt_bf16_kernel<<<2048, blk, 0, stream>>>(x, B0, (int)Md);
    transpose_bf16_kernel<<<dim3(16, 16), blk, 0, stream>>>(Wq,  Wtq,  Dm, Dm);
    transpose_bf16_kernel<<<dim3(16, 16), blk, 0, stream>>>(Wk,  Wtk,  Dm, Dm);
    transpose_bf16_kernel<<<dim3(16, 16), blk, 0, stream>>>(Wv,  Wtv,  Dm, Dm);
    transpose_bf16_kernel<<<dim3(16, 16), blk, 0, stream>>>(Wfq, Wtfq, Dm, Dm);
    transpose_bf16_kernel<<<dim3(16, 16), blk, 0, stream>>>(Wfk, Wtfk, Dm, Dm);
    transpose_bf16_kernel<<<dim3(64, 16), blk, 0, stream>>>(W1,  Wt1,  Dm, Dmlp);
    transpose_bf16_kernel<<<dim3(16, 64), blk, 0, stream>>>(W2,  Wt2,  Dmlp, Dm);
    {
        const int nz = 4096 + 64 * 64 * 64 + 4096;
        zero_kernel<<<(nz + 255) / 256, blk, 0, stream>>>(qp, nz);
    }

    // 1) Q = LN(x@Wq+bq) -> B1 ; K = LN(x@Wk+bk) -> B2
    mfma_gemm256<0, false, false, true, true><<<gA, blk512, 0, stream>>>(
        B0, Dm, Wtq, Dm, bq, B1, nullptr, nullptr, Mrows, Dm, Dm);
    ln1024_bf16_kernel<<<Mrows, blk, 0, stream>>>(B1, B1, gq, betaq);
    mfma_gemm256<0, false, false, true, true><<<gA, blk512, 0, stream>>>(
        B0, Dm, Wtk, Dm, bk, B2, nullptr, nullptr, Mrows, Dm, Dm);
    ln1024_bf16_kernel<<<Mrows, blk, 0, stream>>>(B2, B2, gk, betak);

    // 2) probe softmax gating
    qprobe_kernel<<<dim3(Dm / 256, 16, Bc), blk, 0, stream>>>(B1, qp);
    logits_kernel<<<dim3(Lq / 256, 64), blk, 0, stream>>>(B2, qp, score);
    softmax4097_kernel<<<64, blk, 0, stream>>>(score);

    // 3) phiK -> PK ; phiQ -> PQ
    mfma_gemm256<1, false, false, true, true><<<gA, blk512, 0, stream>>>(
        B2, Dm, Wtfk, Dm, bfk, PK, nullptr, nullptr, Mrows, Dm, Dm);
    mfma_gemm256<1, false, false, true, true><<<gA, blk512, 0, stream>>>(
        B1, Dm, Wtfq, Dm, bfq, PQ, nullptr, nullptr, Mrows, Dm, Dm);

    // 4) V = LN(x@Wv+bv) -> B1
    mfma_gemm256<0, false, false, true, true><<<gA, blk512, 0, stream>>>(
        B0, Dm, Wtv, Dm, bv, B1, nullptr, nullptr, Mrows, Dm, Dm);
    ln1024_bf16_kernel<<<Mrows, blk, 0, stream>>>(B1, B1, gv, betav);

    // 5) KV / Ksum
    kv_kernel<<<dim3(8, 64), blk, 0, stream>>>(PK, B1, score, KV);
    ksum_kernel<<<dim3(8, 64), dim3(64), 0, stream>>>(PK, score, bfk, Ksum);

    // 6) attention out -> B2, attn LN -> a (in B2)
    attnout_kernel<<<dim3(Lq / 64, 64), blk, 0, stream>>>(PQ, KV, Ksum, B2);
    ln1024_bf16_kernel<<<Mrows, blk, 0, stream>>>(B2, B2, ga, ba);

    // 7) MLP, 2 chunks of 2048 hidden (H1 overlays B0+B1)
    u16* H1 = B0;
    for (int c = 0; c < 2; ++c) {
        mfma_gemm256<2, false, false, true, true><<<gM, blk512, 0, stream>>>(
            B2, Dm, Wt1 + (size_t)c * 2048 * Dm, Dm, b1 + c * 2048,
            H1, nullptr, nullptr, Mrows, 2048, Dm);
        if (c == 0) {
            mfma_gemm256<0, false, false, true, false><<<gA, blk512, 0, stream>>>(
                H1, 2048, Wt2 + (size_t)c * 2048, Dmlp, b2,
                outp, nullptr, nullptr, Mrows, Dm, 2048);
        } else {
            mfma_gemm256<0, true, true, false, false><<<gA, blk512, 0, stream>>>(
                H1, 2048, Wt2 + (size_t)c * 2048, Dmlp, nullptr,
                outp, B2, x, Mrows, Dm, 2048);
        }
    }
}

// Round 6
// 782.804 us; speedup vs baseline: 7.0862x; 1.1194x over previous
//
#include <hip/hip_runtime.h>
#include <cstddef>
#include <cstdint>

static constexpr int Bc   = 4;
static constexpr int Lq   = 4096;
static constexpr int Dm   = 1024;
static constexpr int Dmlp = 4096;
static constexpr int Mrows = Bc * Lq;   // 16384
static constexpr int Lk1   = Lq + 1;    // 4097

typedef unsigned short u16;
typedef __bf16 bf16_t;
typedef bf16_t bf16x8 __attribute__((ext_vector_type(8)));
typedef float  f32x4  __attribute__((ext_vector_type(4)));

__device__ __forceinline__ u16 f2b(float f) {
    uint32_t u = __builtin_bit_cast(uint32_t, f);
    return (u16)((u + 0x7FFFu + ((u >> 16) & 1u)) >> 16);
}
__device__ __forceinline__ float b2f(u16 h) {
    uint32_t u = ((uint32_t)h) << 16;
    return __builtin_bit_cast(float, u);
}

#define GLL16(gsrc, ldst) \
    __builtin_amdgcn_global_load_lds( \
        (const __attribute__((address_space(1))) void*)(gsrc), \
        (__attribute__((address_space(3))) void*)(ldst), 16, 0, 0)

// ---------------------------------------------------------------------------
__global__ __launch_bounds__(256)
void zero_kernel(float* __restrict__ p, int n) {
    const int i = blockIdx.x * 256 + threadIdx.x;
    if (i < n) p[i] = 0.0f;
}

__global__ __launch_bounds__(256)
void cvt_bf16_kernel(const float* __restrict__ in, u16* __restrict__ outp, int n) {
    for (int i = (blockIdx.x * 256 + threadIdx.x) * 4; i < n; i += gridDim.x * 256 * 4) {
        float4 v = *(const float4*)&in[i];
        ushort4 o = { f2b(v.x), f2b(v.y), f2b(v.z), f2b(v.w) };
        *(ushort4*)&outp[i] = o;
    }
}

// W [R][C] fp32 -> Wt [C][R] bf16
__global__ __launch_bounds__(256)
void transpose_bf16_kernel(const float* __restrict__ in, u16* __restrict__ outp,
                           int R, int C) {
    __shared__ float tile[64][65];
    const int r0 = blockIdx.y * 64, c0 = blockIdx.x * 64;
    const int t = threadIdx.x;
    const int lr = t >> 2, lc0 = (t & 3) * 16;
    #pragma unroll
    for (int j = 0; j < 4; ++j) {
        float4 v = *(const float4*)&in[(size_t)(r0 + lr) * C + c0 + lc0 + j * 4];
        tile[lr][lc0 + j * 4 + 0] = v.x;
        tile[lr][lc0 + j * 4 + 1] = v.y;
        tile[lr][lc0 + j * 4 + 2] = v.z;
        tile[lr][lc0 + j * 4 + 3] = v.w;
    }
    __syncthreads();
    const int oc = t >> 2, rr0 = (t & 3) * 16;
    union { u16 u[16]; uint4 v[2]; } pk;
    #pragma unroll
    for (int j = 0; j < 16; ++j) pk.u[j] = f2b(tile[rr0 + j][oc]);
    u16* po = &outp[(size_t)(c0 + oc) * R + r0 + rr0];
    *(uint4*)&po[0] = pk.v[0];
    *(uint4*)&po[8] = pk.v[1];
}

// KVT[bh][e][d] = bf16(KV[bh][d][e]) -- per-head 64x64 transpose+convert
__global__ __launch_bounds__(256)
void kvt_cvt_kernel(const float* __restrict__ KV, u16* __restrict__ KVT) {
    const int bh = blockIdx.x;
    __shared__ float t[64][65];
    const int tid = threadIdx.x;
    const int r = tid >> 2, c0 = (tid & 3) * 16;
    const float* src = &KV[(size_t)bh * 4096];
    #pragma unroll
    for (int j = 0; j < 4; ++j) {
        float4 v = *(const float4*)&src[r * 64 + c0 + j * 4];
        t[r][c0 + j * 4 + 0] = v.x;
        t[r][c0 + j * 4 + 1] = v.y;
        t[r][c0 + j * 4 + 2] = v.z;
        t[r][c0 + j * 4 + 3] = v.w;
    }
    __syncthreads();
    const int e = tid >> 2, d0 = (tid & 3) * 16;
    union { u16 u[16]; uint4 v[2]; } pk;
    #pragma unroll
    for (int j = 0; j < 16; ++j) pk.u[j] = f2b(t[d0 + j][e]);
    u16* po = &KVT[(size_t)bh * 4096 + e * 64 + d0];
    *(uint4*)&po[0] = pk.v[0];
    *(uint4*)&po[8] = pk.v[1];
}

// ---------------------------------------------------------------------------
// 256x256 MFMA GEMM, BK=32, ring-4 LDS (128 KiB), counted vmcnt, T2 swizzle,
// XCD block swizzle, setprio. 8 waves (2M x 4N), per-wave 128x64 out.
// ---------------------------------------------------------------------------
template<int ACT, bool RES, bool ACCUM, bool BIAS, bool OBF16>
__global__ __launch_bounds__(512, 1)
void mfma_gemm256(const u16* __restrict__ A, int ldA,
                  const u16* __restrict__ Bt, int ldB,
                  const float* __restrict__ bias,
                  void* __restrict__ Cout,
                  const u16* __restrict__ res1, const float* __restrict__ res2,
                  int M, int N, int K) {
    __shared__ u16 ldsA[4][8192];
    __shared__ u16 ldsB[4][8192];
    const int tid = threadIdx.x;
    const int l   = tid & 63;
    const int w   = tid >> 6;
    const int wm  = w >> 2;
    const int wn  = w & 3;
    const int l16 = l & 15, l4 = l >> 4;

    const int gx = N >> 8;
    int bid = blockIdx.x;
    bid = (bid & 7) * ((int)gridDim.x >> 3) + (bid >> 3);
    const int brow = (bid / gx) << 8;
    const int bcol = (bid % gx) << 8;

    const int srow = w * 16 + (l >> 2);
    const int skof = ((l & 3) ^ ((l >> 3) & 3)) << 3;
    const u16* gA = A  + (size_t)(brow + srow) * ldA + skof;
    const u16* gB = Bt + (size_t)(bcol + srow) * ldB + skof;
    const size_t gsA = (size_t)128 * ldA;
    const size_t gsB = (size_t)128 * ldB;
    const int ldst = w * 512 + l * 8;

    const int koff_rd = ((l4 ^ ((l16 >> 1) & 3)) << 3);
    const int aRdBase = (wm * 128 + l16) * 32 + koff_rd;
    const int bRdBase = (wn * 64  + l16) * 32 + koff_rd;

    f32x4 acc[8][4];
    const f32x4 zf = {0.f, 0.f, 0.f, 0.f};
    #pragma unroll
    for (int m = 0; m < 8; ++m)
        #pragma unroll
        for (int n = 0; n < 4; ++n) acc[m][n] = zf;

    auto stageA = [&](int slot, int kelem) {
        const u16* s = gA + (size_t)kelem;
        GLL16(s,       &ldsA[slot][ldst]);
        GLL16(s + gsA, &ldsA[slot][ldst + 4096]);
    };
    auto stageB = [&](int slot, int kelem) {
        const u16* s = gB + (size_t)kelem;
        GLL16(s,       &ldsB[slot][ldst]);
        GLL16(s + gsB, &ldsB[slot][ldst + 4096]);
    };

    const int T = K >> 5;
    stageA(0, 0);  stageB(0, 0);
    stageA(1, 32); stageB(1, 32);
    stageA(2, 64); stageB(2, 64);

    auto step = [&](int t, int waitsel, bool do_stage) {
        asm volatile("s_waitcnt lgkmcnt(0)" ::: "memory");
        if (waitsel == 0)      asm volatile("s_waitcnt vmcnt(8)" ::: "memory");
        else if (waitsel == 1) asm volatile("s_waitcnt vmcnt(4)" ::: "memory");
        else                   asm volatile("s_waitcnt vmcnt(0)" ::: "memory");
        asm volatile("s_barrier" ::: "memory");
        const int slot = t & 3;
        bf16x8 afr[4], bfr[4];
        #pragma unroll
        for (int n = 0; n < 4; ++n)
            bfr[n] = *(const bf16x8*)&ldsB[slot][bRdBase + n * 512];
        #pragma unroll
        for (int m = 0; m < 4; ++m)
            afr[m] = *(const bf16x8*)&ldsA[slot][aRdBase + m * 512];
        if (do_stage) stageA((t + 3) & 3, (t + 3) * 32);
        __builtin_amdgcn_s_setprio(1);
        #pragma unroll
        for (int m = 0; m < 4; ++m)
            #pragma unroll
            for (int n = 0; n < 4; ++n)
                acc[m][n] = __builtin_amdgcn_mfma_f32_16x16x32_bf16(
                    afr[m], bfr[n], acc[m][n], 0, 0, 0);
        __builtin_amdgcn_s_setprio(0);
        #pragma unroll
        for (int m = 0; m < 4; ++m)
            afr[m] = *(const bf16x8*)&ldsA[slot][aRdBase + (m + 4) * 512];
        if (do_stage) stageB((t + 3) & 3, (t + 3) * 32);
        __builtin_amdgcn_s_setprio(1);
        #pragma unroll
        for (int m = 0; m < 4; ++m)
            #pragma unroll
            for (int n = 0; n < 4; ++n)
                acc[m + 4][n] = __builtin_amdgcn_mfma_f32_16x16x32_bf16(
                    afr[m], bfr[n], acc[m + 4][n], 0, 0, 0);
        __builtin_amdgcn_s_setprio(0);
    };

    for (int t = 0; t < T - 2; ++t) step(t, 0, (t + 3) < T);
    step(T - 2, 1, false);
    step(T - 1, 2, false);

    float bvn[4];
    int coln[4];
    #pragma unroll
    for (int n = 0; n < 4; ++n) {
        coln[n] = bcol + wn * 64 + n * 16 + l16;
        bvn[n] = BIAS ? bias[coln[n]] : 0.f;
    }
    #pragma unroll
    for (int m = 0; m < 8; ++m) {
        #pragma unroll
        for (int q = 0; q < 4; ++q) {
            const size_t row = (size_t)brow + wm * 128 + m * 16 + l4 * 4 + q;
            #pragma unroll
            for (int n = 0; n < 4; ++n) {
                float v = acc[m][n][q] + bvn[n];
                if (ACT == 1) v = tanhf(v) + 1.0f;
                if (ACT == 2) v = 0.5f * v * (1.0f + erff(v * 0.70710678118654752f));
                const size_t idx = row * (size_t)N + coln[n];
                if (OBF16) {
                    ((u16*)Cout)[idx] = f2b(v);
                } else {
                    float* Cf = (float*)Cout;
                    if (ACCUM) v += Cf[idx];
                    if (RES)   v += b2f(res1[idx]) + res2[idx];
                    Cf[idx] = v;
                }
            }
        }
    }
}

// ---------------------------------------------------------------------------
__global__ __launch_bounds__(256)
void ln1024_bf16_kernel(const u16* __restrict__ in, u16* __restrict__ outp,
                        const float* __restrict__ g, const float* __restrict__ be) {
    const size_t base = (size_t)blockIdx.x * Dm;
    const int tid = threadIdx.x;
    ushort4 raw = *(const ushort4*)&in[base + tid * 4];
    float v0 = b2f(raw.x), v1 = b2f(raw.y), v2 = b2f(raw.z), v3 = b2f(raw.w);
    float s  = v0 + v1 + v2 + v3;
    float sq = v0 * v0 + v1 * v1 + v2 * v2 + v3 * v3;
    #pragma unroll
    for (int off = 32; off > 0; off >>= 1) {
        s  += __shfl_down(s,  off, 64);
        sq += __shfl_down(sq, off, 64);
    }
    __shared__ float rs[4], rq[4];
    const int lane = tid & 63, wv = tid >> 6;
    if (lane == 0) { rs[wv] = s; rq[wv] = sq; }
    __syncthreads();
    s  = rs[0] + rs[1] + rs[2] + rs[3];
    sq = rq[0] + rq[1] + rq[2] + rq[3];
    const float mean = s * (1.0f / 1024.0f);
    const float var  = sq * (1.0f / 1024.0f) - mean * mean;
    const float inv  = rsqrtf(var + 1e-5f);
    float4 gv = *(const float4*)&g[tid * 4];
    float4 bv = *(const float4*)&be[tid * 4];
    ushort4 o;
    o.x = f2b((v0 - mean) * inv * gv.x + bv.x);
    o.y = f2b((v1 - mean) * inv * gv.y + bv.y);
    o.z = f2b((v2 - mean) * inv * gv.z + bv.z);
    o.w = f2b((v3 - mean) * inv * gv.w + bv.w);
    *(ushort4*)&outp[base + tid * 4] = o;
}

__global__ __launch_bounds__(256)
void qprobe_kernel(const u16* __restrict__ Q, float* __restrict__ qp) {
    const int b = blockIdx.z;
    const int col = blockIdx.x * 256 + threadIdx.x;
    const int lchunk = Lq / 16;
    const int l0 = blockIdx.y * lchunk;
    const u16* p = Q + ((size_t)b * Lq + l0) * Dm + col;
    float s = 0.f;
    for (int l = 0; l < lchunk; ++l, p += Dm) s += b2f(*p);
    atomicAdd(&qp[b * Dm + col], s * (1.0f / (4096.0f * 8.0f)));
}

__global__ __launch_bounds__(256)
void logits_kernel(const u16* __restrict__ Kc, const float* __restrict__ qp,
                   float* __restrict__ score) {
    const int bh = blockIdx.y, b = bh >> 4, h = bh & 15;
    __shared__ float q[64];
    if (threadIdx.x < 64) q[threadIdx.x] = qp[b * Dm + h * 64 + threadIdx.x];
    __syncthreads();
    const int kr = blockIdx.x * 256 + threadIdx.x;
    const ushort4* krp = (const ushort4*)&Kc[((size_t)b * Lq + kr) * Dm + h * 64];
    float s = 0.f;
    #pragma unroll
    for (int i = 0; i < 16; ++i) {
        ushort4 v = krp[i];
        s += q[i * 4 + 0] * b2f(v.x) + q[i * 4 + 1] * b2f(v.y)
           + q[i * 4 + 2] * b2f(v.z) + q[i * 4 + 3] * b2f(v.w);
    }
    score[(size_t)bh * Lk1 + kr + 1] = s;
    if (blockIdx.x == 0 && threadIdx.x == 0) score[(size_t)bh * Lk1] = 0.f;
}

__global__ __launch_bounds__(256)
void softmax4097_kernel(float* __restrict__ sc) {
    __shared__ float buf[Lk1];
    __shared__ float red[8];
    const size_t base = (size_t)blockIdx.x * Lk1;
    const int tid = threadIdx.x;
    float mx = -1e30f;
    for (int i = tid; i < Lk1; i += 256) { float v = sc[base + i]; buf[i] = v; mx = fmaxf(mx, v); }
    #pragma unroll
    for (int off = 32; off > 0; off >>= 1) mx = fmaxf(mx, __shfl_down(mx, off, 64));
    const int lane = tid & 63, wv = tid >> 6;
    if (lane == 0) red[wv] = mx;
    __syncthreads();
    mx = fmaxf(fmaxf(red[0], red[1]), fmaxf(red[2], red[3]));
    float sum = 0.f;
    for (int i = tid; i < Lk1; i += 256) { float e = expf(buf[i] - mx); buf[i] = e; sum += e; }
    #pragma unroll
    for (int off = 32; off > 0; off >>= 1) sum += __shfl_down(sum, off, 64);
    if (lane == 0) red[4 + wv] = sum;
    __syncthreads();
    sum = red[4] + red[5] + red[6] + red[7];
    const float inv = 1.0f / sum;
    for (int i = tid; i < Lk1; i += 256) sc[base + i] = buf[i] * inv;
}

__global__ __launch_bounds__(256)
void kv_kernel(const u16* __restrict__ phiK, const u16* __restrict__ Vc,
               const float* __restrict__ sc, float* __restrict__ KV) {
    const int bh = blockIdx.y, b = bh >> 4, h = bh & 15;
    const int lchunk = Lq / 8;
    const int l0 = blockIdx.x * lchunk;
    __shared__ float pk[8][64];
    __shared__ float vv[8][64];
    const int i0 = (threadIdx.x >> 4) << 2;
    const int j0 = (threadIdx.x & 15) << 2;
    float acc[4][4] = {};
    for (int lb = l0; lb < l0 + lchunk; lb += 8) {
        #pragma unroll
        for (int q = 0; q < 2; ++q) {
            const int idx = threadIdx.x + q * 256;
            const int r = idx >> 6, c = idx & 63;
            const float scv = sc[(size_t)bh * Lk1 + lb + r + 1];
            const size_t off = ((size_t)b * Lq + lb + r) * Dm + h * 64 + c;
            pk[r][c] = b2f(phiK[off]) * scv;
            vv[r][c] = b2f(Vc[off]);
        }
        __syncthreads();
        #pragma unroll
        for (int r = 0; r < 8; ++r) {
            float ra[4], rb[4];
            #pragma unroll
            for (int i = 0; i < 4; ++i) ra[i] = pk[r][i0 + i];
            #pragma unroll
            for (int j = 0; j < 4; ++j) rb[j] = vv[r][j0 + j];
            #pragma unroll
            for (int i = 0; i < 4; ++i)
                #pragma unroll
                for (int j = 0; j < 4; ++j)
                    acc[i][j] = fmaf(ra[i], rb[j], acc[i][j]);
        }
        __syncthreads();
    }
    #pragma unroll
    for (int i = 0; i < 4; ++i)
        #pragma unroll
        for (int j = 0; j < 4; ++j)
            atomicAdd(&KV[((size_t)bh * 64 + i0 + i) * 64 + j0 + j], acc[i][j]);
}

__global__ __launch_bounds__(64)
void ksum_kernel(const u16* __restrict__ phiK, const float* __restrict__ sc,
                 const float* __restrict__ bfk, float* __restrict__ Ksum) {
    const int bh = blockIdx.y, b = bh >> 4, h = bh & 15;
    const int lchunk = Lq / 8;
    const int l0 = blockIdx.x * lchunk;
    const int dd = threadIdx.x;
    float s = 0.f;
    const u16* pp = &phiK[((size_t)b * Lq + l0) * Dm + h * 64 + dd];
    const float* sp = &sc[(size_t)bh * Lk1 + l0 + 1];
    for (int l = 0; l < lchunk; ++l, pp += Dm) s = fmaf(b2f(*pp), sp[l], s);
    if (blockIdx.x == 0) s += sc[(size_t)bh * Lk1] * (tanhf(bfk[h * 64 + dd]) + 1.0f);
    atomicAdd(&Ksum[bh * 64 + dd], s);
}

// ---------------------------------------------------------------------------
// MFMA attnout: per block (256 rows, one head): out = (phiQ_tile @ KVT^T)/den
// phiQ tile staged in LDS (XOR slot swizzle both-sides), KVT frags from global,
// den from staged tile + Ksum. 4 waves, each 64 rows x 64 cols.
// ---------------------------------------------------------------------------
__global__ __launch_bounds__(256, 2)
void attnout_mfma_kernel(const u16* __restrict__ phiQ, const u16* __restrict__ KVT,
                         const float* __restrict__ Ksum, u16* __restrict__ outp) {
    __shared__ u16 pqs[256 * 64];    // [256 rows][64 d], 16B-slot swizzled
    __shared__ float kss[64];
    __shared__ float dns[256];
    const int bh = blockIdx.y, b = bh >> 4, h = bh & 15;
    const int l0 = blockIdx.x * 256;
    const int tid = threadIdx.x;
    const int l = tid & 63, w = tid >> 6;
    const int l16 = l & 15, l4 = l >> 4;

    // B-fragments from global: KVT[e][d], e = n*16+l16, k = kk*32+l4*8
    bf16x8 bfr[4][2];
    {
        const u16* kb = KVT + (size_t)bh * 4096;
        #pragma unroll
        for (int n = 0; n < 4; ++n)
            #pragma unroll
            for (int kk = 0; kk < 2; ++kk)
                bfr[n][kk] = *(const bf16x8*)&kb[(n * 16 + l16) * 64 + kk * 32 + l4 * 8];
    }
    if (tid < 64) kss[tid] = Ksum[bh * 64 + tid];

    // stage phiQ tile: thread t, issue j: row = j*32 + (t>>3);
    // dest slot = t&7 (linear, = u16 off t*8 + j*2048); src slot = (t&7)^(row&7)
    {
        const int rsub = tid >> 3;
        const int ssrc = ((tid & 7) ^ (rsub & 7)) * 8;
        u16* ldst = &pqs[(size_t)tid * 8];
        #pragma unroll
        for (int j = 0; j < 8; ++j) {
            const u16* g = phiQ + (((size_t)(b * Lq + l0 + j * 32 + rsub)) << 10)
                          + h * 64 + ssrc;
            GLL16(g, ldst + j * 2048);
        }
    }
    __syncthreads();

    // den per row (thread tid -> row tid): slot s holds k = s*8..s*8+7
    {
        const int r7 = tid & 7;
        float s = 0.f;
        #pragma unroll
        for (int sl = 0; sl < 8; ++sl) {
            bf16x8 v = *(const bf16x8*)&pqs[tid * 64 + ((sl ^ r7) << 3)];
            #pragma unroll
            for (int j = 0; j < 8; ++j) s = fmaf(b2f(((u16*)&v)[j]), kss[sl * 8 + j], s);
        }
        dns[tid] = 1.0f / (s + 1e-6f);
    }

    // MFMA: A frag (m,kk): row = w*64+m*16+l16, slot = kk*4+l4, swz ^ (row&7)
    f32x4 acc[4][4];
    const f32x4 zf = {0.f, 0.f, 0.f, 0.f};
    #pragma unroll
    for (int m = 0; m < 4; ++m)
        #pragma unroll
        for (int n = 0; n < 4; ++n) acc[m][n] = zf;
    #pragma unroll
    for (int kk = 0; kk < 2; ++kk) {
        bf16x8 afr[4];
        #pragma unroll
        for (int m = 0; m < 4; ++m) {
            const int row = w * 64 + m * 16 + l16;
            afr[m] = *(const bf16x8*)&pqs[row * 64 + (((kk * 4 + l4) ^ (row & 7)) << 3)];
        }
        #pragma unroll
        for (int m = 0; m < 4; ++m)
            #pragma unroll
            for (int n = 0; n < 4; ++n)
                acc[m][n] = __builtin_amdgcn_mfma_f32_16x16x32_bf16(
                    afr[m], bfr[n][kk], acc[m][n], 0, 0, 0);
    }
    __syncthreads();   // dns visible

    #pragma unroll
    for (int m = 0; m < 4; ++m) {
        #pragma unroll
        for (int q = 0; q < 4; ++q) {
            const int rl = w * 64 + m * 16 + l4 * 4 + q;
            const float dn = dns[rl];
            const size_t rowg = ((size_t)(b * Lq + l0 + rl)) << 10;
            #pragma unroll
            for (int n = 0; n < 4; ++n)
                outp[rowg + h * 64 + n * 16 + l16] = f2b(acc[m][n][q] * dn);
        }
    }
}

// ---------------------------------------------------------------------------
extern "C" void kernel_launch(void* const* d_in, const int* in_sizes, int n_in,
                              void* d_out, int out_size, void* d_ws, size_t ws_size,
                              hipStream_t stream) {
    const float* x     = (const float*)d_in[0];
    const float* Wq    = (const float*)d_in[1];
    const float* bq    = (const float*)d_in[2];
    const float* gq    = (const float*)d_in[3];
    const float* betaq = (const float*)d_in[4];
    const float* Wk    = (const float*)d_in[5];
    const float* bk    = (const float*)d_in[6];
    const float* gk    = (const float*)d_in[7];
    const float* betak = (const float*)d_in[8];
    const float* Wv    = (const float*)d_in[9];
    const float* bv    = (const float*)d_in[10];
    const float* gv    = (const float*)d_in[11];
    const float* betav = (const float*)d_in[12];
    const float* Wfq   = (const float*)d_in[13];
    const float* bfq   = (const float*)d_in[14];
    const float* Wfk   = (const float*)d_in[15];
    const float* bfk   = (const float*)d_in[16];
    const float* ga    = (const float*)d_in[17];
    const float* ba    = (const float*)d_in[18];
    const float* W1    = (const float*)d_in[19];
    const float* b1    = (const float*)d_in[20];
    const float* W2    = (const float*)d_in[21];
    const float* b2    = (const float*)d_in[22];
    float* outp = (float*)d_out;

    uint8_t* wsb = (uint8_t*)d_ws;
    size_t off = 0;
    auto alloc = [&](size_t bytes) { void* p = wsb + off; off += bytes; return p; };
    const size_t Md = (size_t)Mrows * Dm;
    u16* B0   = (u16*)alloc(Md * 2);
    u16* B1   = (u16*)alloc(Md * 2);
    u16* B2   = (u16*)alloc(Md * 2);
    u16* Wtq  = (u16*)alloc((size_t)Dm * Dm * 2);
    u16* Wtk  = (u16*)alloc((size_t)Dm * Dm * 2);
    u16* Wtv  = (u16*)alloc((size_t)Dm * Dm * 2);
    u16* Wtfq = (u16*)alloc((size_t)Dm * Dm * 2);
    u16* Wtfk = (u16*)alloc((size_t)Dm * Dm * 2);
    u16* Wt1  = (u16*)alloc((size_t)Dm * Dmlp * 2);
    u16* Wt2  = (u16*)alloc((size_t)Dm * Dmlp * 2);
    float* qp    = (float*)alloc(4096 * 4);
    float* KV    = (float*)alloc((size_t)64 * 64 * 64 * 4);
    float* Ksum  = (float*)alloc(4096 * 4);
    float* score = (float*)alloc((size_t)64 * Lk1 * 4);
    u16* KVT     = (u16*)alloc((size_t)64 * 64 * 64 * 2);
    u16* PK = (u16*)outp;
    u16* PQ = (u16*)outp + Md;

    const dim3 blk(256);
    const dim3 blk512(512);
    const dim3 gA(256);   // (16384/256)*(1024/256)
    const dim3 gM(512);   // (16384/256)*(2048/256)

    cvt_bf16_kernel<<<2048, blk, 0, stream>>>(x, B0, (int)Md);
    transpose_bf16_kernel<<<dim3(16, 16), blk, 0, stream>>>(Wq,  Wtq,  Dm, Dm);
    transpose_bf16_kernel<<<dim3(16, 16), blk, 0, stream>>>(Wk,  Wtk,  Dm, Dm);
    transpose_bf16_kernel<<<dim3(16, 16), blk, 0, stream>>>(Wv,  Wtv,  Dm, Dm);
    transpose_bf16_kernel<<<dim3(16, 16), blk, 0, stream>>>(Wfq, Wtfq, Dm, Dm);
    transpose_bf16_kernel<<<dim3(16, 16), blk, 0, stream>>>(Wfk, Wtfk, Dm, Dm);
    transpose_bf16_kernel<<<dim3(64, 16), blk, 0, stream>>>(W1,  Wt1,  Dm, Dmlp);
    transpose_bf16_kernel<<<dim3(16, 64), blk, 0, stream>>>(W2,  Wt2,  Dmlp, Dm);
    {
        const int nz = 4096 + 64 * 64 * 64 + 4096;
        zero_kernel<<<(nz + 255) / 256, blk, 0, stream>>>(qp, nz);
    }

    // 1) Q = LN(x@Wq+bq) -> B1 ; K = LN(x@Wk+bk) -> B2
    mfma_gemm256<0, false, false, true, true><<<gA, blk512, 0, stream>>>(
        B0, Dm, Wtq, Dm, bq, B1, nullptr, nullptr, Mrows, Dm, Dm);
    ln1024_bf16_kernel<<<Mrows, blk, 0, stream>>>(B1, B1, gq, betaq);
    mfma_gemm256<0, false, false, true, true><<<gA, blk512, 0, stream>>>(
        B0, Dm, Wtk, Dm, bk, B2, nullptr, nullptr, Mrows, Dm, Dm);
    ln1024_bf16_kernel<<<Mrows, blk, 0, stream>>>(B2, B2, gk, betak);

    // 2) probe softmax gating
    qprobe_kernel<<<dim3(Dm / 256, 16, Bc), blk, 0, stream>>>(B1, qp);
    logits_kernel<<<dim3(Lq / 256, 64), blk, 0, stream>>>(B2, qp, score);
    softmax4097_kernel<<<64, blk, 0, stream>>>(score);

    // 3) phiK -> PK ; phiQ -> PQ
    mfma_gemm256<1, false, false, true, true><<<gA, blk512, 0, stream>>>(
        B2, Dm, Wtfk, Dm, bfk, PK, nullptr, nullptr, Mrows, Dm, Dm);
    mfma_gemm256<1, false, false, true, true><<<gA, blk512, 0, stream>>>(
        B1, Dm, Wtfq, Dm, bfq, PQ, nullptr, nullptr, Mrows, Dm, Dm);

    // 4) V = LN(x@Wv+bv) -> B1
    mfma_gemm256<0, false, false, true, true><<<gA, blk512, 0, stream>>>(
        B0, Dm, Wtv, Dm, bv, B1, nullptr, nullptr, Mrows, Dm, Dm);
    ln1024_bf16_kernel<<<Mrows, blk, 0, stream>>>(B1, B1, gv, betav);

    // 5) KV / Ksum, then KV -> KVT bf16
    kv_kernel<<<dim3(8, 64), blk, 0, stream>>>(PK, B1, score, KV);
    ksum_kernel<<<dim3(8, 64), dim3(64), 0, stream>>>(PK, score, bfk, Ksum);
    kvt_cvt_kernel<<<64, blk, 0, stream>>>(KV, KVT);

    // 6) attention out (MFMA) -> B2, attn LN -> a (in B2)
    attnout_mfma_kernel<<<dim3(Lq / 256, 64), blk, 0, stream>>>(PQ, KVT, Ksum, B2);
    ln1024_bf16_kernel<<<Mrows, blk, 0, stream>>>(B2, B2, ga, ba);

    // 7) MLP, 2 chunks of 2048 hidden (H1 overlays B0+B1)
    u16* H1 = B0;
    for (int c = 0; c < 2; ++c) {
        mfma_gemm256<2, false, false, true, true><<<gM, blk512, 0, stream>>>(
            B2, Dm, Wt1 + (size_t)c * 2048 * Dm, Dm, b1 + c * 2048,
            H1, nullptr, nullptr, Mrows, 2048, Dm);
        if (c == 0) {
            mfma_gemm256<0, false, false, true, false><<<gA, blk512, 0, stream>>>(
                H1, 2048, Wt2 + (size_t)c * 2048, Dmlp, b2,
                outp, nullptr, nullptr, Mrows, Dm, 2048);
        } else {
            mfma_gemm256<0, true, true, false, false><<<gA, blk512, 0, stream>>>(
                H1, 2048, Wt2 + (size_t)c * 2048, Dmlp, nullptr,
                outp, B2, x, Mrows, Dm, 2048);
        }
    }
}